// Round 19
// baseline (209.263 us; speedup 1.0000x reference)
//
#include <hip/hip_runtime.h>
#include <math.h>

typedef unsigned short u16;
typedef unsigned int u32;
typedef __attribute__((ext_vector_type(8))) short short8;
typedef __attribute__((ext_vector_type(4))) float f32x4;
typedef __attribute__((ext_vector_type(16))) float f32x16;
typedef __attribute__((ext_vector_type(4))) u32 u32x4;
typedef __attribute__((ext_vector_type(2))) u32 u32x2;

__device__ inline u16 f2b(float f) {
  u32 u = __builtin_bit_cast(u32, f);
  u32 r = u + 0x7fffu + ((u >> 16) & 1u);
  return (u16)(r >> 16);
}
__device__ inline float b2f(u16 b) {
  return __builtin_bit_cast(float, (u32)b << 16);
}
// HW packed f32->bf16 (RTNE), 1 instruction for 2 values
__device__ inline u32 cvtpk(float lo, float hi) {
  u32 r;
  asm("v_cvt_pk_bf16_f32 %0, %1, %2" : "=v"(r) : "v"(lo), "v"(hi));
  return r;
}
__device__ inline float eluf(float x) { return x > 0.f ? x : expf(x) - 1.f; }

__device__ inline f32x4 mfma16(short8 a, short8 b, f32x4 c) {
  return __builtin_amdgcn_mfma_f32_16x16x32_bf16(a, b, c, 0, 0, 0);
}
__device__ inline f32x16 mfma32(short8 a, short8 b, f32x16 c) {
  return __builtin_amdgcn_mfma_f32_32x32x16_bf16(a, b, c, 0, 0, 0);
}
__device__ inline void gload16(const u16* g, u16* l) {
  __builtin_amdgcn_global_load_lds((__attribute__((address_space(1))) void*)(g),
                                   (__attribute__((address_space(3))) void*)(l),
                                   16, 0, 0);
}

// ---------------------------------------------------------------------------
// prep_misc: prep_pe + pb_bias + EW + WEFF/bias_t + transw (all one launch)
// ---------------------------------------------------------------------------
__global__ __launch_bounds__(256) void prep_misc(
    const float* __restrict__ emb_b, const float* __restrict__ bq,
    const float* __restrict__ bk, const float* __restrict__ bv,
    const float* __restrict__ Wq, const float* __restrict__ Wk,
    const float* __restrict__ Wv, const float* __restrict__ embW,
    const float* __restrict__ Wo, const float* __restrict__ bo,
    const float* __restrict__ w1, u16* __restrict__ A_pe,
    float* __restrict__ pb_bias, float* __restrict__ EW,
    u16* __restrict__ WEFFT, float* __restrict__ bias_t,
    u16* __restrict__ WTqkv) {
  __shared__ float smem[64 * 65];
  const int bid = blockIdx.x, t = threadIdx.x;
  if (bid < 512) {
    int s = bid;
    float div = __expf((2.f * t) * (-9.210340371976184f / 512.f));
    float arg = (float)s * div;
    A_pe[s * 512 + 2 * t] = f2b(__sinf(arg) + emb_b[2 * t]);
    A_pe[s * 512 + 2 * t + 1] = f2b(__cosf(arg) + emb_b[2 * t + 1]);
  } else if (bid < 536) {
    int i = (bid - 512) * 256 + t;  // 0..6143
    int z = i >> 9, e = i & 511;
    int ty = z >> 2, m = z & 3;
    const float* bp = (ty == 0) ? bq : (ty == 1) ? bk : bv;
    pb_bias[i] = bp[m * 512 + e];
  } else if (bid < 584) {
    int idx = bid - 536;
    int z = idx >> 2, ch = idx & 3;
    const float* W =
        ((z < 4) ? Wq : (z < 8) ? Wk : Wv) + (long)(z & 3) * 262144;
    int el = t & 127, dh = t >> 7;
    int e = ch * 128 + el;
    float a[4] = {};
    for (int d = dh * 256; d < dh * 256 + 256; ++d) {
      float wv = W[(long)d * 512 + e];
#pragma unroll
      for (int f = 0; f < 4; ++f) a[f] += embW[f * 512 + d] * wv;
    }
#pragma unroll
    for (int f = 0; f < 4; ++f) smem[(dh * 4 + f) * 128 + el] = a[f];
    __syncthreads();
    if (t < 128) {
#pragma unroll
      for (int f = 0; f < 4; ++f)
        EW[((long)z * 4 + f) * 512 + e] =
            smem[f * 128 + el] + smem[(4 + f) * 128 + el];
    }
  } else if (bid < 1097) {
    const int wb = bid - 584;  // 0..512
    const int w = t >> 6, l = t & 63;
    if (wb < 512) {
      int idx = wb * 4 + w;  // 0..2047
      int m = idx >> 9, d = idx & 511;
      const float* wrow = Wo + ((long)m * 512 + d) * 512;
      float a[15] = {};
#pragma unroll
      for (int i = 0; i < 8; ++i) {
        int e = l * 8 + i;
        float wv = wrow[e];
#pragma unroll
        for (int o = 0; o < 5; ++o)
#pragma unroll
          for (int k = 0; k < 3; ++k)
            a[o * 3 + k] += wv * w1[((long)o * 2048 + m * 512 + e) * 3 + k];
      }
#pragma unroll
      for (int j = 0; j < 15; ++j) {
        float v = a[j];
        for (int o = 1; o < 64; o <<= 1) v += __shfl_xor(v, o);
        if (l == 0) WEFFT[((long)m * 16 + j) * 512 + d] = f2b(v);
      }
      if (l == 0) WEFFT[((long)m * 16 + 15) * 512 + d] = 0;
    } else if (w == 0) {
      float a[15] = {};
      for (int c = l; c < 2048; c += 64) {
        float bv = bo[c];
#pragma unroll
        for (int o = 0; o < 5; ++o)
#pragma unroll
          for (int k = 0; k < 3; ++k)
            a[o * 3 + k] += bv * w1[((long)o * 2048 + c) * 3 + k];
      }
#pragma unroll
      for (int j = 0; j < 15; ++j) {
        float v = a[j];
        for (int o = 1; o < 64; o <<= 1) v += __shfl_xor(v, o);
        if (l == 0) bias_t[j] = v;
      }
      if (l == 0) bias_t[15] = 0.f;
    }
  } else {
    // transw: bf16-transpose one 64x64 tile of one QKV weight matrix
    int bidt = bid - 1097;  // 0..767
    int mid = bidt >> 6, rest = bidt & 63;
    int d0 = (rest >> 3) * 64, e0 = (rest & 7) * 64;
    const float* W =
        ((mid < 4) ? Wq : (mid < 8) ? Wk : Wv) + (long)(mid & 3) * 262144;
    u16* WT = WTqkv + (long)mid * 262144;
    float(*tile)[65] = (float(*)[65])smem;
    int dr = t >> 2, ec = (t & 3) * 16;
#pragma unroll
    for (int j = 0; j < 16; j += 4) {
      float4 v = *(const float4*)&W[(long)(d0 + dr) * 512 + e0 + ec + j];
      tile[dr][ec + j] = v.x;
      tile[dr][ec + j + 1] = v.y;
      tile[dr][ec + j + 2] = v.z;
      tile[dr][ec + j + 3] = v.w;
    }
    __syncthreads();
    int er = t >> 2, dc = (t & 3) * 16;
    u16 tmp[16] __attribute__((aligned(16)));
#pragma unroll
    for (int j = 0; j < 16; ++j) tmp[j] = f2b(tile[dc + j][er]);
    *(short8*)&WT[(long)(e0 + er) * 512 + d0 + dc] = *(short8*)&tmp[0];
    *(short8*)&WT[(long)(e0 + er) * 512 + d0 + dc + 8] = *(short8*)&tmp[8];
  }
}

// ---------------------------------------------------------------------------
// bf16 GEMM; 3-deep LDS pipeline, one barrier per K-step, fully unrolled.
// ---------------------------------------------------------------------------
template <bool OBF>
__global__ __launch_bounds__(256) void gemm_bt(
    const u16* __restrict__ A, long sAz, int lda, const u16* __restrict__ BT,
    const float* __restrict__ bias, void* __restrict__ out, long sOz, int ldo) {
  __shared__ u16 As[3][128 * 32];
  __shared__ u16 Bs[3][128 * 32];
  const int z = blockIdx.z;
  const int tid = threadIdx.x, w = tid >> 6, l = tid & 63;
  const long row0 = (long)blockIdx.y * 128;
  const u16* Ab = A + (long)z * sAz + row0 * lda;
  const u16* Bb = BT + (long)z * 262144 + (long)blockIdx.x * 128 * 512;
  const u16* ga = Ab + (long)(w * 32 + (l >> 2)) * lda + (l & 3) * 8;
  const u16* gb = Bb + (long)(w * 32 + (l >> 2)) * 512 + (l & 3) * 8;
  f32x4 acc[4][4] = {};
  const int wr = (w >> 1) * 64, wc = (w & 1) * 64;

#define GSTAGE(BF, KT)                                                        \
  {                                                                           \
    gload16(ga + (KT)*32, &As[BF][w * 32 * 32]);                              \
    gload16(ga + (KT)*32 + 16 * lda, &As[BF][w * 32 * 32 + 16 * 32]);         \
    gload16(gb + (KT)*32, &Bs[BF][w * 32 * 32]);                              \
    gload16(gb + (KT)*32 + 16 * 512, &Bs[BF][w * 32 * 32 + 16 * 32]);         \
  }

#define GTILE(KT, CUR, NXT)                                                   \
  {                                                                           \
    if ((KT) < 15) {                                                          \
      GSTAGE(NXT, (KT) + 1);                                                  \
      asm volatile("s_waitcnt vmcnt(4)" ::: "memory");                        \
    } else {                                                                  \
      asm volatile("s_waitcnt vmcnt(0)" ::: "memory");                        \
    }                                                                         \
    __builtin_amdgcn_s_barrier();                                             \
    __builtin_amdgcn_sched_barrier(0);                                        \
    short8 af[4], bf[4];                                                      \
    _Pragma("unroll") for (int i = 0; i < 4; ++i) af[i] =                     \
        *(const short8*)&As[CUR][(wr + i * 16 + (l & 15)) * 32 +              \
                                 (l >> 4) * 8];                               \
    _Pragma("unroll") for (int i = 0; i < 4; ++i) bf[i] =                     \
        *(const short8*)&Bs[CUR][(wc + i * 16 + (l & 15)) * 32 +              \
                                 (l >> 4) * 8];                               \
    _Pragma("unroll") for (int i = 0; i < 4; ++i) _Pragma("unroll")           \
        for (int j = 0; j < 4; ++j) acc[i][j] =                               \
            mfma16(af[i], bf[j], acc[i][j]);                                  \
    __builtin_amdgcn_sched_barrier(0);                                        \
  }

  GSTAGE(0, 0);
  GTILE(0, 0, 1);  GTILE(1, 1, 2);  GTILE(2, 2, 0);  GTILE(3, 0, 1);
  GTILE(4, 1, 2);  GTILE(5, 2, 0);  GTILE(6, 0, 1);  GTILE(7, 1, 2);
  GTILE(8, 2, 0);  GTILE(9, 0, 1);  GTILE(10, 1, 2); GTILE(11, 2, 0);
  GTILE(12, 0, 1); GTILE(13, 1, 2); GTILE(14, 2, 0); GTILE(15, 0, 1);
#undef GTILE
#undef GSTAGE

  const int colB = blockIdx.x * 128 + wc;
#pragma unroll
  for (int i = 0; i < 4; ++i)
#pragma unroll
    for (int j = 0; j < 4; ++j) {
      int col = colB + j * 16 + (l & 15);
      float bb = bias[(long)z * 512 + col];
#pragma unroll
      for (int q = 0; q < 4; ++q) {
        long r = row0 + wr + i * 16 + (l >> 4) * 4 + q;
        float v = acc[i][j][q] + bb;
        if (OBF)
          ((u16*)out)[(long)z * sOz + r * ldo + col] = f2b(v);
        else
          ((float*)out)[(long)z * sOz + r * ldo + col] = v;
      }
    }
}

// ---------------------------------------------------------------------------
// fused KV + V-transpose (Q generated inside attention).
// ---------------------------------------------------------------------------
__global__ __launch_bounds__(256) void kv_fused(
    const float* __restrict__ x, const float* __restrict__ EW,
    const u16* __restrict__ PB, u16* __restrict__ K, u16* __restrict__ VT,
    long mstride) {
  __shared__ float ews[2][4][64];
  __shared__ u16 vtile[64][72];
  const int bh = blockIdx.x;  // b*8+h
  const int st = blockIdx.y;
  const int m = blockIdx.z;
  const int b = bh >> 3, h = bh & 7;
  const int hoff = h * 64;
  const int t = threadIdx.x;
  if (t < 128) {
    int ir = t >> 6, dk = t & 63;  // ir: 0=K(z=4+m), 1=V(z=8+m)
    int z = (ir + 1) * 4 + m;
#pragma unroll
    for (int f = 0; f < 4; ++f)
      ews[ir][f][dk] = EW[((long)z * 4 + f) * 512 + hoff + dk];
  }
  __syncthreads();
  const int sr = t >> 2, cq = t & 3;
  const int s = st * 64 + sr;
  const long rid = (long)b * 512 + s;
  const float* xr = x + rid * 7;
  const float xd = xr[3 + m], x0 = xr[0], x1 = xr[1], x2 = xr[2];
  const long obase = (long)m * mstride + rid * 512 + hoff + cq * 16;

  float res[2][16];
#pragma unroll
  for (int ir = 0; ir < 2; ++ir) {
    int z = (ir + 1) * 4 + m;
    const u16* pbp = PB + (((long)z * 512 + s)) * 512 + hoff + cq * 16;
    short8 pbv0 = *(const short8*)pbp;
    short8 pbv1 = *(const short8*)(pbp + 8);
#pragma unroll
    for (int j = 0; j < 16; ++j) {
      int dk = cq * 16 + j;
      u16 pb = (u16)(j < 8 ? pbv0[j] : pbv1[j - 8]);
      res[ir][j] = xd * ews[ir][0][dk] + x0 * ews[ir][1][dk] +
                   x1 * ews[ir][2][dk] + x2 * ews[ir][3][dk] + b2f(pb);
    }
  }
  {
    float ss = 0.f;
#pragma unroll
    for (int j = 0; j < 16; ++j) ss += res[0][j] * res[0][j];
    ss += __shfl_xor(ss, 1);
    ss += __shfl_xor(ss, 2);
    float sc = 1.f / fmaxf(sqrtf(ss), 1e-12f);
    u32 o[8];
#pragma unroll
    for (int jj = 0; jj < 8; ++jj)
      o[jj] = cvtpk(res[0][2 * jj] * sc, res[0][2 * jj + 1] * sc);
    *(u32x4*)&K[obase] = *(u32x4*)&o[0];
    *(u32x4*)&K[obase + 8] = *(u32x4*)&o[4];
  }
  {
    u32 o[8];
#pragma unroll
    for (int jj = 0; jj < 8; ++jj)
      o[jj] = cvtpk(res[1][2 * jj], res[1][2 * jj + 1]);
    *(short8*)&vtile[sr][cq * 16] = *(short8*)&o[0];
    *(short8*)&vtile[sr][cq * 16 + 8] = *(short8*)&o[4];
  }
  __syncthreads();
  {
    int kr = t >> 2, sc2 = (t & 3) * 16;
    u16 tmp[16] __attribute__((aligned(16)));
#pragma unroll
    for (int j = 0; j < 16; ++j) tmp[j] = vtile[sc2 + j][kr];
    long gdst = (long)m * mstride + ((long)bh * 64 + kr) * 512 + st * 64 + sc2;
    *(short8*)&VT[gdst] = *(short8*)&tmp[0];
    *(short8*)&VT[gdst + 8] = *(short8*)&tmp[8];
  }
}

// ---------------------------------------------------------------------------
// flash attention, max-free, 32x32 swapped-operand; 8-wave blocks; XCD
// swizzle; 3-deep LDS pipeline, ONE barrier per tile, fully unrolled.
// Q generated in-block, pack-early; ewsq stored [64][4] (one b128 per fma
// group), x coop-staged in LDS (one load per row, b128 broadcast consume).
// ---------------------------------------------------------------------------
__global__ __launch_bounds__(512, 4) void attn_kernel(
    const float* __restrict__ x, const float* __restrict__ EW,
    const u16* __restrict__ PB, const u16* __restrict__ Kg,
    const u16* __restrict__ VTg, u16* __restrict__ ctxg, long mstride) {
  __shared__ u16 Kb[3][64][64];
  __shared__ u16 Vb[3][64][64];
  __shared__ float ewsq[64][4];
  __shared__ float xs[256][4];
  const int wgid = (blockIdx.x & 7) * 256 + (blockIdx.x >> 3);
  const int qp = wgid & 1;        // 0..1, 256 q-rows each
  const int mz = wgid >> 1;
  const int m = mz & 3;           // module
  const int bh = mz >> 2;         // b*8+h
  const u16* K = Kg + (long)m * mstride;
  const u16* VT = VTg + (long)m * mstride;
  u16* ctx = ctxg + (long)m * mstride;
  const int b = bh >> 3, h = bh & 7;
  const int tid = threadIdx.x, w = tid >> 6, l = tid & 63;
  const int lq = l & 31, hi = l >> 5, l7 = l & 7;
  const long rowbase = (long)b * 512;
  const int hoff = h * 64;
  const int rw = l >> 3, gch = (l & 7) ^ rw;
  const int qrow = qp * 256 + w * 32;

  const u16* Kgbase = K + rowbase * 512 + hoff + gch * 8;
  const u16* Vgbase = VT + (long)bh * 64 * 512 + gch * 8;

#define STAGE(bf, kt)                                                         \
  {                                                                           \
    int rr = w * 8;                                                           \
    gload16(Kgbase + (long)((kt)*64 + rr + rw) * 512, &Kb[bf][rr][0]);        \
    gload16(Vgbase + (long)(rr + rw) * 512 + (kt)*64, &Vb[bf][rr][0]);        \
  }

  // stage x rows (threads 0-255) and Q's EW slice transposed (threads 256+)
  if (tid < 256) {
    const float* xr = x + (rowbase + qp * 256 + tid) * 7;
    xs[tid][0] = xr[3 + m];
    xs[tid][1] = xr[0];
    xs[tid][2] = xr[1];
    xs[tid][3] = xr[2];
  } else {
    int q = tid - 256;  // 0..255
    int dk = q >> 2, f = q & 3;
    ewsq[dk][f] = EW[((long)m * 4 + f) * 512 + hoff + dk];
  }
  STAGE(0, 0);  // tile-0 loads fly under Q-gen
  __syncthreads();

  // Q-gen, pack-early: row s_q = qrow+lq, dk = dc*16+hi*8+j
  short8 qf[4];
  {
    const int rib = w * 32 + lq;  // row within block
    float4 xv = *(const float4*)&xs[rib][0];
    const u16* pbq =
        PB + ((long)m * 512 + qp * 256 + rib) * 512 + hoff + hi * 8;
    u32 qpk[16];
    float ss = 0.f;
#pragma unroll
    for (int dc = 0; dc < 4; ++dc) {
      short8 pbv = *(const short8*)(pbq + dc * 16);
      float v[8];
#pragma unroll
      for (int j = 0; j < 8; ++j) {
        int dk = dc * 16 + hi * 8 + j;
        float4 e = *(const float4*)&ewsq[dk][0];
        v[j] = xv.x * e.x + xv.y * e.y + xv.z * e.z + xv.w * e.w +
               b2f((u16)pbv[j]);
        ss += v[j] * v[j];
      }
#pragma unroll
      for (int jj = 0; jj < 4; ++jj)
        qpk[dc * 4 + jj] = cvtpk(v[2 * jj], v[2 * jj + 1]);
    }
    ss += __shfl_xor(ss, 32);  // partner holds the complementary 32 dk
    float sc = 1.f / fmaxf(sqrtf(ss), 1e-12f);
#pragma unroll
    for (int dc = 0; dc < 4; ++dc) {
      u32x4 pk;
#pragma unroll
      for (int jj = 0; jj < 4; ++jj) {
        u32 pv = qpk[dc * 4 + jj];
        pk[jj] = cvtpk(b2f((u16)pv) * sc, b2f((u16)(pv >> 16)) * sc);
      }
      qf[dc] = __builtin_bit_cast(short8, pk);
    }
  }

  short8 ones;
#pragma unroll
  for (int i = 0; i < 8; ++i) ones[i] = (short)0x3F80;  // bf16 1.0

  f32x16 o_acc[2] = {};
  f32x16 l_acc = {};

#define TILE(KT, CUR, NXT)                                                    \
  {                                                                           \
    if ((KT) < 7) {                                                           \
      STAGE(NXT, (KT) + 1);                                                   \
      asm volatile("s_waitcnt vmcnt(2)" ::: "memory");                        \
    } else {                                                                  \
      asm volatile("s_waitcnt vmcnt(0)" ::: "memory");                        \
    }                                                                         \
    __builtin_amdgcn_s_barrier();                                             \
    __builtin_amdgcn_sched_barrier(0);                                        \
    __builtin_amdgcn_s_setprio(1);                                            \
    _Pragma("unroll") for (int ktile = 0; ktile < 2; ++ktile) {               \
      f32x16 s = {};                                                          \
      _Pragma("unroll") for (int dc = 0; dc < 4; ++dc) {                      \
        short8 kf = *(const short8*)((const char*)&Kb[CUR][ktile * 32 + lq]   \
                                         [0] +                                \
                                     (((dc * 2 + hi) ^ l7) * 16));            \
        s = mfma32(kf, qf[dc], s);                                            \
      }                                                                       \
      float p[16];                                                            \
      _Pragma("unroll") for (int r = 0; r < 16; ++r) p[r] = __expf(s[r]);     \
      u32 s0a = cvtpk(p[0], p[1]), s0b = cvtpk(p[4], p[5]);                   \
      u32 s1a = cvtpk(p[2], p[3]), s1b = cvtpk(p[6], p[7]);                   \
      u32 s2a = cvtpk(p[8], p[9]), s2b = cvtpk(p[12], p[13]);                 \
      u32 s3a = cvtpk(p[10], p[11]), s3b = cvtpk(p[14], p[15]);               \
      asm("v_permlane32_swap_b32 %0, %1" : "+v"(s0a), "+v"(s0b));             \
      asm("v_permlane32_swap_b32 %0, %1" : "+v"(s1a), "+v"(s1b));             \
      asm("v_permlane32_swap_b32 %0, %1" : "+v"(s2a), "+v"(s2b));             \
      asm("v_permlane32_swap_b32 %0, %1" : "+v"(s3a), "+v"(s3b));             \
      u32x4 f0v = {s0a, s1a, s0b, s1b};                                       \
      u32x4 f1v = {s2a, s3a, s2b, s3b};                                       \
      short8 bf0 = __builtin_bit_cast(short8, f0v);                           \
      short8 bf1 = __builtin_bit_cast(short8, f1v);                           \
      _Pragma("unroll") for (int kk2 = 0; kk2 < 2; ++kk2) {                   \
        const int kc = ktile * 2 + kk2;                                       \
        short8 pb = kk2 ? bf1 : bf0;                                          \
        l_acc = mfma32(ones, pb, l_acc);                                      \
        _Pragma("unroll") for (int dt = 0; dt < 2; ++dt) {                    \
          short8 vf =                                                         \
              *(const short8*)((const char*)&Vb[CUR][dt * 32 + lq][0] +       \
                               (((kc * 2 + hi) ^ l7) * 16));                  \
          o_acc[dt] = mfma32(vf, pb, o_acc[dt]);                              \
        }                                                                     \
      }                                                                       \
    }                                                                         \
    __builtin_amdgcn_s_setprio(0);                                            \
    __builtin_amdgcn_sched_barrier(0);                                        \
  }

  TILE(0, 0, 1);
  TILE(1, 1, 2);
  TILE(2, 2, 0);
  TILE(3, 0, 1);
  TILE(4, 1, 2);
  TILE(5, 2, 0);
  TILE(6, 0, 1);
  TILE(7, 1, 2);
#undef TILE
#undef STAGE
  const float inv = 1.f / l_acc[0];
  u16* crow = ctx + (rowbase + qrow + lq) * 512 + hoff + hi * 4;
#pragma unroll
  for (int dt = 0; dt < 2; ++dt)
#pragma unroll
    for (int rq = 0; rq < 4; ++rq) {
      u32 w0 = cvtpk(o_acc[dt][rq * 4 + 0] * inv, o_acc[dt][rq * 4 + 1] * inv);
      u32 w1 = cvtpk(o_acc[dt][rq * 4 + 2] * inv, o_acc[dt][rq * 4 + 3] * inv);
      u32x2 pr = {w0, w1};
      *(u32x2*)&crow[dt * 32 + rq * 8] = pr;
    }
}

// ---------------------------------------------------------------------------
// t[r][j] = sum_m ctx_m[r][:] . WEFFT[m][j][:]
// ---------------------------------------------------------------------------
__global__ __launch_bounds__(64) void t_gemm(const u16* __restrict__ ctx4,
                                             const u16* __restrict__ WEFFT,
                                             float* __restrict__ t) {
  const int l = threadIdx.x;
  const long r0 = (long)blockIdx.x * 16;
  f32x4 acc = {};
#pragma unroll
  for (int m = 0; m < 4; ++m) {
    const u16* A =
        ctx4 + (long)m * 8388608 + (r0 + (l & 15)) * 512 + (l >> 4) * 8;
    const u16* Bb = WEFFT + m * 8192 + (l & 15) * 512 + (l >> 4) * 8;
#pragma unroll
    for (int kt = 0; kt < 16; ++kt) {
      short8 af = *(const short8*)(A + kt * 32);
      short8 bf = *(const short8*)(Bb + kt * 32);
      acc = mfma16(af, bf, acc);
    }
  }
#pragma unroll
  for (int q = 0; q < 4; ++q)
    t[(r0 + (l >> 4) * 4 + q) * 16 + (l & 15)] = acc[q];
}

// ---------------------------------------------------------------------------
// tail_fused: c1 + conv2 + pool + fc1/fc2/fc3 + LN — one block per batch
// ---------------------------------------------------------------------------
__global__ __launch_bounds__(512) void tail_fused(
    const float* __restrict__ t, const float* __restrict__ bias_t,
    const float* __restrict__ b1, const float* __restrict__ w2,
    const float* __restrict__ b2, const float* __restrict__ fw1,
    const float* __restrict__ fb1, const float* __restrict__ fw2,
    const float* __restrict__ fb2, const float* __restrict__ fw3,
    const float* __restrict__ fb3, const float* __restrict__ g,
    const float* __restrict__ be, float* __restrict__ out) {
  __shared__ float ts[512][16];
  __shared__ float c1s[5][512];
  __shared__ float flat[512];
  __shared__ float z1p[2][256];
  __shared__ float z1[256];
  __shared__ float z2p[2][128];
  __shared__ float z2[128];
  __shared__ float z3[96];
  int b = blockIdx.x, tid = threadIdx.x;
  const float4* tsrc = (const float4*)(t + (long)b * 8192);
  float4* tdst = (float4*)&ts[0][0];
#pragma unroll
  for (int i = 0; i < 4; ++i) tdst[tid + i * 512] = tsrc[tid + i * 512];
  __syncthreads();
#pragma unroll
  for (int i = 0; i < 5; ++i) {
    int idx = tid + i * 512;  // 0..2559
    int o = idx >> 9, s = idx & 511;
    float a = b1[o];
#pragma unroll
    for (int k = 0; k < 3; ++k) {
      int ss = s + k - 1;
      if (ss >= 0 && ss < 512) a += ts[ss][o * 3 + k] + bias_t[o * 3 + k];
    }
    c1s[o][s] = eluf(a);
  }
  __syncthreads();
  {
    int r = tid;  // 0..511
    int o = r >> 8, sp = r & 255;
    float mx = -1e30f;
#pragma unroll
    for (int sd = 0; sd < 2; ++sd) {
      int s = sp * 2 + sd;
      float a = b2[o];
#pragma unroll
      for (int ic = 0; ic < 5; ++ic)
#pragma unroll
        for (int k = 0; k < 3; ++k) {
          int ss = s + k - 1;
          if (ss >= 0 && ss < 512) a += c1s[ic][ss] * w2[(o * 5 + ic) * 3 + k];
        }
      mx = fmaxf(mx, eluf(a));
    }
    flat[r] = mx;
  }
  __syncthreads();
  {
    int o = tid & 255, part = tid >> 8;
    float a = 0.f;
    const float* wp = fw1 + (long)part * 256 * 256 + o;
    const float* xp = flat + part * 256;
#pragma unroll 8
    for (int i = 0; i < 256; ++i) a += xp[i] * wp[i * 256];
    z1p[part][o] = a;
  }
  __syncthreads();
  if (tid < 256) z1[tid] = eluf(fb1[tid] + z1p[0][tid] + z1p[1][tid]);
  __syncthreads();
  if (tid < 256) {
    int o = tid & 127, part = tid >> 7;
    float a = 0.f;
    const float* wp = fw2 + (long)part * 128 * 128 + o;
    const float* xp = z1 + part * 128;
#pragma unroll 8
    for (int i = 0; i < 128; ++i) a += xp[i] * wp[i * 128];
    z2p[part][o] = a;
  }
  __syncthreads();
  if (tid < 128) z2[tid] = eluf(fb2[tid] + z2p[0][tid] + z2p[1][tid]);
  __syncthreads();
  if (tid < 96) {
    float a = fb3[tid];
#pragma unroll 8
    for (int i = 0; i < 128; ++i) a += z2[i] * fw3[i * 96 + tid];
    z3[tid] = a;
  }
  __syncthreads();
  if (tid < 96) {
    float mu = 0.f;
    for (int j = 0; j < 96; ++j) mu += z3[j];
    mu *= (1.f / 96.f);
    float sq = 0.f;
    for (int j = 0; j < 96; ++j) {
      float d = z3[j] - mu;
      sq += d * d;
    }
    float var = sq * (1.f / 96.f);
    out[b * 96 + tid] = (z3[tid] - mu) / sqrtf(var + 1e-5f) * g[tid] + be[tid];
  }
}

// ---------------------------------------------------------------------------
extern "C" void kernel_launch(void* const* d_in, const int* in_sizes, int n_in,
                              void* d_out, int out_size, void* d_ws,
                              size_t ws_size, hipStream_t stream) {
  (void)in_sizes; (void)n_in; (void)out_size;
  const float* x    = (const float*)d_in[0];
  const float* embW = (const float*)d_in[1];
  const float* embB = (const float*)d_in[2];
  const float* Wq   = (const float*)d_in[3];
  const float* bq   = (const float*)d_in[4];
  const float* Wk   = (const float*)d_in[5];
  const float* bk   = (const float*)d_in[6];
  const float* Wv   = (const float*)d_in[7];
  const float* bv   = (const float*)d_in[8];
  const float* Wo   = (const float*)d_in[9];
  const float* bo   = (const float*)d_in[10];
  const float* c1w  = (const float*)d_in[11];
  const float* c1b  = (const float*)d_in[12];
  const float* c2w  = (const float*)d_in[13];
  const float* c2b  = (const float*)d_in[14];
  const float* f1w  = (const float*)d_in[15];
  const float* f1b  = (const float*)d_in[16];
  const float* f2w  = (const float*)d_in[17];
  const float* f2b_ = (const float*)d_in[18];
  const float* f3w  = (const float*)d_in[19];
  const float* f3b  = (const float*)d_in[20];
  const float* lng  = (const float*)d_in[21];
  const float* lnb  = (const float*)d_in[22];
  float* out = (float*)d_out;

  char* p = (char*)d_ws;
  const size_t NEED = 215736384;
  if (ws_size < NEED) return;
  const long MS = 8388608;  // per-module stride in u16 elements (16 MB)

  u16*   A_pe    = (u16*)(p + 0);
  u16*   WTqkv   = (u16*)(p + 524288);
  float* pb_bias = (float*)(p + 6815744);
  float* EW      = (float*)(p + 6840320);
  u16*   PB      = (u16*)(p + 6938624);
  u16*   ctx4    = (u16*)(p + 13230080);   // 4 x 16.77 MB (attn output)
  u16*   K4      = (u16*)(p + 80338944);
  u16*   VT4     = (u16*)(p + 147447808);
  u16*   WEFFT   = (u16*)(p + 214556672);
  float* bias_t  = (float*)(p + 214622208);
  float* t_buf   = (float*)(p + 214622272);

  prep_misc<<<1865, 256, 0, stream>>>(embB, bq, bk, bv, Wq, Wk, Wv, embW, Wo,
                                      bo, c1w, A_pe, pb_bias, EW, WEFFT,
                                      bias_t, WTqkv);
  gemm_bt<true><<<dim3(4, 4, 12), 256, 0, stream>>>(
      A_pe, 0, 512, WTqkv, pb_bias, (void*)PB, 262144, 512);

  kv_fused<<<dim3(256, 8, 4), 256, 0, stream>>>(x, EW, PB, K4, VT4, MS);
  attn_kernel<<<2048, 512, 0, stream>>>(x, EW, PB, K4, VT4, ctx4, MS);

  t_gemm<<<1024, 64, 0, stream>>>(ctx4, WEFFT, t_buf);
  tail_fused<<<32, 512, 0, stream>>>(t_buf, bias_t, c1b, c2w, c2b, f1w, f1b,
                                     f2w, f2b_, f3w, f3b, lng, lnb, out);
}

// Round 20
// 202.541 us; speedup vs baseline: 1.0332x; 1.0332x over previous
//
#include <hip/hip_runtime.h>
#include <math.h>

typedef unsigned short u16;
typedef unsigned int u32;
typedef __attribute__((ext_vector_type(8))) short short8;
typedef __attribute__((ext_vector_type(4))) float f32x4;
typedef __attribute__((ext_vector_type(16))) float f32x16;
typedef __attribute__((ext_vector_type(4))) u32 u32x4;
typedef __attribute__((ext_vector_type(2))) u32 u32x2;

__device__ inline u16 f2b(float f) {
  u32 u = __builtin_bit_cast(u32, f);
  u32 r = u + 0x7fffu + ((u >> 16) & 1u);
  return (u16)(r >> 16);
}
__device__ inline float b2f(u16 b) {
  return __builtin_bit_cast(float, (u32)b << 16);
}
// HW packed f32->bf16 (RTNE), 1 instruction for 2 values
__device__ inline u32 cvtpk(float lo, float hi) {
  u32 r;
  asm("v_cvt_pk_bf16_f32 %0, %1, %2" : "=v"(r) : "v"(lo), "v"(hi));
  return r;
}
__device__ inline float eluf(float x) { return x > 0.f ? x : expf(x) - 1.f; }

__device__ inline f32x4 mfma16(short8 a, short8 b, f32x4 c) {
  return __builtin_amdgcn_mfma_f32_16x16x32_bf16(a, b, c, 0, 0, 0);
}
__device__ inline f32x16 mfma32(short8 a, short8 b, f32x16 c) {
  return __builtin_amdgcn_mfma_f32_32x32x16_bf16(a, b, c, 0, 0, 0);
}
__device__ inline void gload16(const u16* g, u16* l) {
  __builtin_amdgcn_global_load_lds((__attribute__((address_space(1))) void*)(g),
                                   (__attribute__((address_space(3))) void*)(l),
                                   16, 0, 0);
}

// ---------------------------------------------------------------------------
// prep_misc: prep_pe + pb_bias + EW + WEFF/bias_t + transw (all one launch)
// ---------------------------------------------------------------------------
__global__ __launch_bounds__(256) void prep_misc(
    const float* __restrict__ emb_b, const float* __restrict__ bq,
    const float* __restrict__ bk, const float* __restrict__ bv,
    const float* __restrict__ Wq, const float* __restrict__ Wk,
    const float* __restrict__ Wv, const float* __restrict__ embW,
    const float* __restrict__ Wo, const float* __restrict__ bo,
    const float* __restrict__ w1, u16* __restrict__ A_pe,
    float* __restrict__ pb_bias, float* __restrict__ EW,
    u16* __restrict__ WEFFT, float* __restrict__ bias_t,
    u16* __restrict__ WTqkv) {
  __shared__ float smem[64 * 65];
  const int bid = blockIdx.x, t = threadIdx.x;
  if (bid < 512) {
    int s = bid;
    float div = __expf((2.f * t) * (-9.210340371976184f / 512.f));
    float arg = (float)s * div;
    A_pe[s * 512 + 2 * t] = f2b(__sinf(arg) + emb_b[2 * t]);
    A_pe[s * 512 + 2 * t + 1] = f2b(__cosf(arg) + emb_b[2 * t + 1]);
  } else if (bid < 536) {
    int i = (bid - 512) * 256 + t;  // 0..6143
    int z = i >> 9, e = i & 511;
    int ty = z >> 2, m = z & 3;
    const float* bp = (ty == 0) ? bq : (ty == 1) ? bk : bv;
    pb_bias[i] = bp[m * 512 + e];
  } else if (bid < 584) {
    int idx = bid - 536;
    int z = idx >> 2, ch = idx & 3;
    const float* W =
        ((z < 4) ? Wq : (z < 8) ? Wk : Wv) + (long)(z & 3) * 262144;
    int el = t & 127, dh = t >> 7;
    int e = ch * 128 + el;
    float a[4] = {};
    for (int d = dh * 256; d < dh * 256 + 256; ++d) {
      float wv = W[(long)d * 512 + e];
#pragma unroll
      for (int f = 0; f < 4; ++f) a[f] += embW[f * 512 + d] * wv;
    }
#pragma unroll
    for (int f = 0; f < 4; ++f) smem[(dh * 4 + f) * 128 + el] = a[f];
    __syncthreads();
    if (t < 128) {
#pragma unroll
      for (int f = 0; f < 4; ++f)
        EW[((long)z * 4 + f) * 512 + e] =
            smem[f * 128 + el] + smem[(4 + f) * 128 + el];
    }
  } else if (bid < 1097) {
    const int wb = bid - 584;  // 0..512
    const int w = t >> 6, l = t & 63;
    if (wb < 512) {
      int idx = wb * 4 + w;  // 0..2047
      int m = idx >> 9, d = idx & 511;
      const float* wrow = Wo + ((long)m * 512 + d) * 512;
      float a[15] = {};
#pragma unroll
      for (int i = 0; i < 8; ++i) {
        int e = l * 8 + i;
        float wv = wrow[e];
#pragma unroll
        for (int o = 0; o < 5; ++o)
#pragma unroll
          for (int k = 0; k < 3; ++k)
            a[o * 3 + k] += wv * w1[((long)o * 2048 + m * 512 + e) * 3 + k];
      }
#pragma unroll
      for (int j = 0; j < 15; ++j) {
        float v = a[j];
        for (int o = 1; o < 64; o <<= 1) v += __shfl_xor(v, o);
        if (l == 0) WEFFT[((long)m * 16 + j) * 512 + d] = f2b(v);
      }
      if (l == 0) WEFFT[((long)m * 16 + 15) * 512 + d] = 0;
    } else if (w == 0) {
      float a[15] = {};
      for (int c = l; c < 2048; c += 64) {
        float bv = bo[c];
#pragma unroll
        for (int o = 0; o < 5; ++o)
#pragma unroll
          for (int k = 0; k < 3; ++k)
            a[o * 3 + k] += bv * w1[((long)o * 2048 + c) * 3 + k];
      }
#pragma unroll
      for (int j = 0; j < 15; ++j) {
        float v = a[j];
        for (int o = 1; o < 64; o <<= 1) v += __shfl_xor(v, o);
        if (l == 0) bias_t[j] = v;
      }
      if (l == 0) bias_t[15] = 0.f;
    }
  } else {
    // transw: bf16-transpose one 64x64 tile of one QKV weight matrix
    int bidt = bid - 1097;  // 0..767
    int mid = bidt >> 6, rest = bidt & 63;
    int d0 = (rest >> 3) * 64, e0 = (rest & 7) * 64;
    const float* W =
        ((mid < 4) ? Wq : (mid < 8) ? Wk : Wv) + (long)(mid & 3) * 262144;
    u16* WT = WTqkv + (long)mid * 262144;
    float(*tile)[65] = (float(*)[65])smem;
    int dr = t >> 2, ec = (t & 3) * 16;
#pragma unroll
    for (int j = 0; j < 16; j += 4) {
      float4 v = *(const float4*)&W[(long)(d0 + dr) * 512 + e0 + ec + j];
      tile[dr][ec + j] = v.x;
      tile[dr][ec + j + 1] = v.y;
      tile[dr][ec + j + 2] = v.z;
      tile[dr][ec + j + 3] = v.w;
    }
    __syncthreads();
    int er = t >> 2, dc = (t & 3) * 16;
    u16 tmp[16] __attribute__((aligned(16)));
#pragma unroll
    for (int j = 0; j < 16; ++j) tmp[j] = f2b(tile[dc + j][er]);
    *(short8*)&WT[(long)(e0 + er) * 512 + d0 + dc] = *(short8*)&tmp[0];
    *(short8*)&WT[(long)(e0 + er) * 512 + d0 + dc + 8] = *(short8*)&tmp[8];
  }
}

// ---------------------------------------------------------------------------
// bf16 GEMM; 3-deep LDS pipeline, one barrier per K-step, fully unrolled.
// ---------------------------------------------------------------------------
template <bool OBF>
__global__ __launch_bounds__(256) void gemm_bt(
    const u16* __restrict__ A, long sAz, int lda, const u16* __restrict__ BT,
    const float* __restrict__ bias, void* __restrict__ out, long sOz, int ldo) {
  __shared__ u16 As[3][128 * 32];
  __shared__ u16 Bs[3][128 * 32];
  const int z = blockIdx.z;
  const int tid = threadIdx.x, w = tid >> 6, l = tid & 63;
  const long row0 = (long)blockIdx.y * 128;
  const u16* Ab = A + (long)z * sAz + row0 * lda;
  const u16* Bb = BT + (long)z * 262144 + (long)blockIdx.x * 128 * 512;
  const u16* ga = Ab + (long)(w * 32 + (l >> 2)) * lda + (l & 3) * 8;
  const u16* gb = Bb + (long)(w * 32 + (l >> 2)) * 512 + (l & 3) * 8;
  f32x4 acc[4][4] = {};
  const int wr = (w >> 1) * 64, wc = (w & 1) * 64;

#define GSTAGE(BF, KT)                                                        \
  {                                                                           \
    gload16(ga + (KT)*32, &As[BF][w * 32 * 32]);                              \
    gload16(ga + (KT)*32 + 16 * lda, &As[BF][w * 32 * 32 + 16 * 32]);         \
    gload16(gb + (KT)*32, &Bs[BF][w * 32 * 32]);                              \
    gload16(gb + (KT)*32 + 16 * 512, &Bs[BF][w * 32 * 32 + 16 * 32]);         \
  }

#define GTILE(KT, CUR, NXT)                                                   \
  {                                                                           \
    if ((KT) < 15) {                                                          \
      GSTAGE(NXT, (KT) + 1);                                                  \
      asm volatile("s_waitcnt vmcnt(4)" ::: "memory");                        \
    } else {                                                                  \
      asm volatile("s_waitcnt vmcnt(0)" ::: "memory");                        \
    }                                                                         \
    __builtin_amdgcn_s_barrier();                                             \
    __builtin_amdgcn_sched_barrier(0);                                        \
    short8 af[4], bf[4];                                                      \
    _Pragma("unroll") for (int i = 0; i < 4; ++i) af[i] =                     \
        *(const short8*)&As[CUR][(wr + i * 16 + (l & 15)) * 32 +              \
                                 (l >> 4) * 8];                               \
    _Pragma("unroll") for (int i = 0; i < 4; ++i) bf[i] =                     \
        *(const short8*)&Bs[CUR][(wc + i * 16 + (l & 15)) * 32 +              \
                                 (l >> 4) * 8];                               \
    _Pragma("unroll") for (int i = 0; i < 4; ++i) _Pragma("unroll")           \
        for (int j = 0; j < 4; ++j) acc[i][j] =                               \
            mfma16(af[i], bf[j], acc[i][j]);                                  \
    __builtin_amdgcn_sched_barrier(0);                                        \
  }

  GSTAGE(0, 0);
  GTILE(0, 0, 1);  GTILE(1, 1, 2);  GTILE(2, 2, 0);  GTILE(3, 0, 1);
  GTILE(4, 1, 2);  GTILE(5, 2, 0);  GTILE(6, 0, 1);  GTILE(7, 1, 2);
  GTILE(8, 2, 0);  GTILE(9, 0, 1);  GTILE(10, 1, 2); GTILE(11, 2, 0);
  GTILE(12, 0, 1); GTILE(13, 1, 2); GTILE(14, 2, 0); GTILE(15, 0, 1);
#undef GTILE
#undef GSTAGE

  const int colB = blockIdx.x * 128 + wc;
#pragma unroll
  for (int i = 0; i < 4; ++i)
#pragma unroll
    for (int j = 0; j < 4; ++j) {
      int col = colB + j * 16 + (l & 15);
      float bb = bias[(long)z * 512 + col];
#pragma unroll
      for (int q = 0; q < 4; ++q) {
        long r = row0 + wr + i * 16 + (l >> 4) * 4 + q;
        float v = acc[i][j][q] + bb;
        if (OBF)
          ((u16*)out)[(long)z * sOz + r * ldo + col] = f2b(v);
        else
          ((float*)out)[(long)z * sOz + r * ldo + col] = v;
      }
    }
}

// ---------------------------------------------------------------------------
// fused KV + V-transpose (Q generated inside attention).
// ---------------------------------------------------------------------------
__global__ __launch_bounds__(256) void kv_fused(
    const float* __restrict__ x, const float* __restrict__ EW,
    const u16* __restrict__ PB, u16* __restrict__ K, u16* __restrict__ VT,
    long mstride) {
  __shared__ float ews[2][4][64];
  __shared__ u16 vtile[64][72];
  const int bh = blockIdx.x;  // b*8+h
  const int st = blockIdx.y;
  const int m = blockIdx.z;
  const int b = bh >> 3, h = bh & 7;
  const int hoff = h * 64;
  const int t = threadIdx.x;
  if (t < 128) {
    int ir = t >> 6, dk = t & 63;  // ir: 0=K(z=4+m), 1=V(z=8+m)
    int z = (ir + 1) * 4 + m;
#pragma unroll
    for (int f = 0; f < 4; ++f)
      ews[ir][f][dk] = EW[((long)z * 4 + f) * 512 + hoff + dk];
  }
  __syncthreads();
  const int sr = t >> 2, cq = t & 3;
  const int s = st * 64 + sr;
  const long rid = (long)b * 512 + s;
  const float* xr = x + rid * 7;
  const float xd = xr[3 + m], x0 = xr[0], x1 = xr[1], x2 = xr[2];
  const long obase = (long)m * mstride + rid * 512 + hoff + cq * 16;

  float res[2][16];
#pragma unroll
  for (int ir = 0; ir < 2; ++ir) {
    int z = (ir + 1) * 4 + m;
    const u16* pbp = PB + (((long)z * 512 + s)) * 512 + hoff + cq * 16;
    short8 pbv0 = *(const short8*)pbp;
    short8 pbv1 = *(const short8*)(pbp + 8);
#pragma unroll
    for (int j = 0; j < 16; ++j) {
      int dk = cq * 16 + j;
      u16 pb = (u16)(j < 8 ? pbv0[j] : pbv1[j - 8]);
      res[ir][j] = xd * ews[ir][0][dk] + x0 * ews[ir][1][dk] +
                   x1 * ews[ir][2][dk] + x2 * ews[ir][3][dk] + b2f(pb);
    }
  }
  {
    float ss = 0.f;
#pragma unroll
    for (int j = 0; j < 16; ++j) ss += res[0][j] * res[0][j];
    ss += __shfl_xor(ss, 1);
    ss += __shfl_xor(ss, 2);
    float sc = 1.f / fmaxf(sqrtf(ss), 1e-12f);
    u32 o[8];
#pragma unroll
    for (int jj = 0; jj < 8; ++jj)
      o[jj] = cvtpk(res[0][2 * jj] * sc, res[0][2 * jj + 1] * sc);
    *(u32x4*)&K[obase] = *(u32x4*)&o[0];
    *(u32x4*)&K[obase + 8] = *(u32x4*)&o[4];
  }
  {
    u32 o[8];
#pragma unroll
    for (int jj = 0; jj < 8; ++jj)
      o[jj] = cvtpk(res[1][2 * jj], res[1][2 * jj + 1]);
    *(short8*)&vtile[sr][cq * 16] = *(short8*)&o[0];
    *(short8*)&vtile[sr][cq * 16 + 8] = *(short8*)&o[4];
  }
  __syncthreads();
  {
    int kr = t >> 2, sc2 = (t & 3) * 16;
    u16 tmp[16] __attribute__((aligned(16)));
#pragma unroll
    for (int j = 0; j < 16; ++j) tmp[j] = vtile[sc2 + j][kr];
    long gdst = (long)m * mstride + ((long)bh * 64 + kr) * 512 + st * 64 + sc2;
    *(short8*)&VT[gdst] = *(short8*)&tmp[0];
    *(short8*)&VT[gdst + 8] = *(short8*)&tmp[8];
  }
}

// ---------------------------------------------------------------------------
// flash attention, max-free, 32x32 swapped-operand; 8-wave blocks; XCD
// swizzle; 3-deep LDS pipeline, ONE barrier per tile, fully unrolled.
// Q generated in-block (pack-early, ewsq[64][4] b128 reads, direct x reads).
// ctx written as 16B stores after permlane pairing (lanes l / l+32 hold the
// same q-row; 4 swaps/dt gather contiguous 8-dk runs) — bit-exact values.
// ---------------------------------------------------------------------------
__global__ __launch_bounds__(512, 4) void attn_kernel(
    const float* __restrict__ x, const float* __restrict__ EW,
    const u16* __restrict__ PB, const u16* __restrict__ Kg,
    const u16* __restrict__ VTg, u16* __restrict__ ctxg, long mstride) {
  __shared__ u16 Kb[3][64][64];
  __shared__ u16 Vb[3][64][64];
  __shared__ float ewsq[64][4];
  const int wgid = (blockIdx.x & 7) * 256 + (blockIdx.x >> 3);
  const int qp = wgid & 1;        // 0..1, 256 q-rows each
  const int mz = wgid >> 1;
  const int m = mz & 3;           // module
  const int bh = mz >> 2;         // b*8+h
  const u16* K = Kg + (long)m * mstride;
  const u16* VT = VTg + (long)m * mstride;
  u16* ctx = ctxg + (long)m * mstride;
  const int b = bh >> 3, h = bh & 7;
  const int tid = threadIdx.x, w = tid >> 6, l = tid & 63;
  const int lq = l & 31, hi = l >> 5, l7 = l & 7;
  const long rowbase = (long)b * 512;
  const int hoff = h * 64;
  const int rw = l >> 3, gch = (l & 7) ^ rw;
  const int qrow = qp * 256 + w * 32;

  const u16* Kgbase = K + rowbase * 512 + hoff + gch * 8;
  const u16* Vgbase = VT + (long)bh * 64 * 512 + gch * 8;

#define STAGE(bf, kt)                                                         \
  {                                                                           \
    int rr = w * 8;                                                           \
    gload16(Kgbase + (long)((kt)*64 + rr + rw) * 512, &Kb[bf][rr][0]);        \
    gload16(Vgbase + (long)(rr + rw) * 512 + (kt)*64, &Vb[bf][rr][0]);        \
  }

  // stage Q's EW slice transposed [64][4]
  if (tid < 256) {
    int dk = tid >> 2, f = tid & 3;
    ewsq[dk][f] = EW[((long)m * 4 + f) * 512 + hoff + dk];
  }
  STAGE(0, 0);  // tile-0 loads fly under Q-gen
  __syncthreads();

  // Q-gen, pack-early: row s_q = qrow+lq, dk = dc*16+hi*8+j
  short8 qf[4];
  {
    const int s_q = qrow + lq;
    const float* xr = x + (rowbase + s_q) * 7;
    const float xd = xr[3 + m], x0 = xr[0], x1 = xr[1], x2 = xr[2];
    const u16* pbq = PB + ((long)m * 512 + s_q) * 512 + hoff + hi * 8;
    u32 qpk[16];
    float ss = 0.f;
#pragma unroll
    for (int dc = 0; dc < 4; ++dc) {
      short8 pbv = *(const short8*)(pbq + dc * 16);
      float v[8];
#pragma unroll
      for (int j = 0; j < 8; ++j) {
        int dk = dc * 16 + hi * 8 + j;
        float4 e = *(const float4*)&ewsq[dk][0];
        v[j] = xd * e.x + x0 * e.y + x1 * e.z + x2 * e.w + b2f((u16)pbv[j]);
        ss += v[j] * v[j];
      }
#pragma unroll
      for (int jj = 0; jj < 4; ++jj)
        qpk[dc * 4 + jj] = cvtpk(v[2 * jj], v[2 * jj + 1]);
    }
    ss += __shfl_xor(ss, 32);  // partner holds the complementary 32 dk
    float sc = 1.f / fmaxf(sqrtf(ss), 1e-12f);
#pragma unroll
    for (int dc = 0; dc < 4; ++dc) {
      u32x4 pk;
#pragma unroll
      for (int jj = 0; jj < 4; ++jj) {
        u32 pv = qpk[dc * 4 + jj];
        pk[jj] = cvtpk(b2f((u16)pv) * sc, b2f((u16)(pv >> 16)) * sc);
      }
      qf[dc] = __builtin_bit_cast(short8, pk);
    }
  }

  short8 ones;
#pragma unroll
  for (int i = 0; i < 8; ++i) ones[i] = (short)0x3F80;  // bf16 1.0

  f32x16 o_acc[2] = {};
  f32x16 l_acc = {};

#define TILE(KT, CUR, NXT)                                                    \
  {                                                                           \
    if ((KT) < 7) {                                                           \
      STAGE(NXT, (KT) + 1);                                                   \
      asm volatile("s_waitcnt vmcnt(2)" ::: "memory");                        \
    } else {                                                                  \
      asm volatile("s_waitcnt vmcnt(0)" ::: "memory");                        \
    }                                                                         \
    __builtin_amdgcn_s_barrier();                                             \
    __builtin_amdgcn_sched_barrier(0);                                        \
    __builtin_amdgcn_s_setprio(1);                                            \
    _Pragma("unroll") for (int ktile = 0; ktile < 2; ++ktile) {               \
      f32x16 s = {};                                                          \
      _Pragma("unroll") for (int dc = 0; dc < 4; ++dc) {                      \
        short8 kf = *(const short8*)((const char*)&Kb[CUR][ktile * 32 + lq]   \
                                         [0] +                                \
                                     (((dc * 2 + hi) ^ l7) * 16));            \
        s = mfma32(kf, qf[dc], s);                                            \
      }                                                                       \
      float p[16];                                                            \
      _Pragma("unroll") for (int r = 0; r < 16; ++r) p[r] = __expf(s[r]);     \
      u32 s0a = cvtpk(p[0], p[1]), s0b = cvtpk(p[4], p[5]);                   \
      u32 s1a = cvtpk(p[2], p[3]), s1b = cvtpk(p[6], p[7]);                   \
      u32 s2a = cvtpk(p[8], p[9]), s2b = cvtpk(p[12], p[13]);                 \
      u32 s3a = cvtpk(p[10], p[11]), s3b = cvtpk(p[14], p[15]);               \
      asm("v_permlane32_swap_b32 %0, %1" : "+v"(s0a), "+v"(s0b));             \
      asm("v_permlane32_swap_b32 %0, %1" : "+v"(s1a), "+v"(s1b));             \
      asm("v_permlane32_swap_b32 %0, %1" : "+v"(s2a), "+v"(s2b));             \
      asm("v_permlane32_swap_b32 %0, %1" : "+v"(s3a), "+v"(s3b));             \
      u32x4 f0v = {s0a, s1a, s0b, s1b};                                       \
      u32x4 f1v = {s2a, s3a, s2b, s3b};                                       \
      short8 bf0 = __builtin_bit_cast(short8, f0v);                           \
      short8 bf1 = __builtin_bit_cast(short8, f1v);                           \
      _Pragma("unroll") for (int kk2 = 0; kk2 < 2; ++kk2) {                   \
        const int kc = ktile * 2 + kk2;                                       \
        short8 pb = kk2 ? bf1 : bf0;                                          \
        l_acc = mfma32(ones, pb, l_acc);                                      \
        _Pragma("unroll") for (int dt = 0; dt < 2; ++dt) {                    \
          short8 vf =                                                         \
              *(const short8*)((const char*)&Vb[CUR][dt * 32 + lq][0] +       \
                               (((kc * 2 + hi) ^ l7) * 16));                  \
          o_acc[dt] = mfma32(vf, pb, o_acc[dt]);                              \
        }                                                                     \
      }                                                                       \
    }                                                                         \
    __builtin_amdgcn_s_setprio(0);                                            \
    __builtin_amdgcn_sched_barrier(0);                                        \
  }

  TILE(0, 0, 1);
  TILE(1, 1, 2);
  TILE(2, 2, 0);
  TILE(3, 0, 1);
  TILE(4, 1, 2);
  TILE(5, 2, 0);
  TILE(6, 0, 1);
  TILE(7, 1, 2);
#undef TILE
#undef STAGE
  // epilogue: 16B coalesced ctx stores via permlane pairing.
  // dk(o_acc[dt][r]) = dt*32 + (r&3) + 8*(r>>2) + 4*hi; lanes l and l+32
  // hold the same q-row. swap(g0,g2),(g1,g3): X'=[X.lo|Y.lo], Y'=[X.hi|Y.hi]
  // -> hi0 lane owns dk 0..15, hi1 lane owns dk 16..31 of each 32-dk half.
  const float inv = 1.f / l_acc[0];
  u16* crow = ctx + (rowbase + qrow + lq) * 512 + hoff;
#pragma unroll
  for (int dt = 0; dt < 2; ++dt) {
    u32 g00 = cvtpk(o_acc[dt][0] * inv, o_acc[dt][1] * inv);
    u32 g01 = cvtpk(o_acc[dt][2] * inv, o_acc[dt][3] * inv);
    u32 g10 = cvtpk(o_acc[dt][4] * inv, o_acc[dt][5] * inv);
    u32 g11 = cvtpk(o_acc[dt][6] * inv, o_acc[dt][7] * inv);
    u32 g20 = cvtpk(o_acc[dt][8] * inv, o_acc[dt][9] * inv);
    u32 g21 = cvtpk(o_acc[dt][10] * inv, o_acc[dt][11] * inv);
    u32 g30 = cvtpk(o_acc[dt][12] * inv, o_acc[dt][13] * inv);
    u32 g31 = cvtpk(o_acc[dt][14] * inv, o_acc[dt][15] * inv);
    asm("v_permlane32_swap_b32 %0, %1" : "+v"(g00), "+v"(g20));
    asm("v_permlane32_swap_b32 %0, %1" : "+v"(g01), "+v"(g21));
    asm("v_permlane32_swap_b32 %0, %1" : "+v"(g10), "+v"(g30));
    asm("v_permlane32_swap_b32 %0, %1" : "+v"(g11), "+v"(g31));
    u32x4 st0 = {g00, g01, g20, g21};
    u32x4 st1 = {g10, g11, g30, g31};
    const int base = dt * 32 + hi * 16;
    *(u32x4*)&crow[base] = st0;
    *(u32x4*)&crow[base + 8] = st1;
  }
}

// ---------------------------------------------------------------------------
// t[r][j] = sum_m ctx_m[r][:] . WEFFT[m][j][:]
// ---------------------------------------------------------------------------
__global__ __launch_bounds__(64) void t_gemm(const u16* __restrict__ ctx4,
                                             const u16* __restrict__ WEFFT,
                                             float* __restrict__ t) {
  const int l = threadIdx.x;
  const long r0 = (long)blockIdx.x * 16;
  f32x4 acc = {};
#pragma unroll
  for (int m = 0; m < 4; ++m) {
    const u16* A =
        ctx4 + (long)m * 8388608 + (r0 + (l & 15)) * 512 + (l >> 4) * 8;
    const u16* Bb = WEFFT + m * 8192 + (l & 15) * 512 + (l >> 4) * 8;
#pragma unroll
    for (int kt = 0; kt < 16; ++kt) {
      short8 af = *(const short8*)(A + kt * 32);
      short8 bf = *(const short8*)(Bb + kt * 32);
      acc = mfma16(af, bf, acc);
    }
  }
#pragma unroll
  for (int q = 0; q < 4; ++q)
    t[(r0 + (l >> 4) * 4 + q) * 16 + (l & 15)] = acc[q];
}

// ---------------------------------------------------------------------------
// tail_fused: c1 + conv2 + pool + fc1/fc2/fc3 + LN — one block per batch
// ---------------------------------------------------------------------------
__global__ __launch_bounds__(512) void tail_fused(
    const float* __restrict__ t, const float* __restrict__ bias_t,
    const float* __restrict__ b1, const float* __restrict__ w2,
    const float* __restrict__ b2, const float* __restrict__ fw1,
    const float* __restrict__ fb1, const float* __restrict__ fw2,
    const float* __restrict__ fb2, const float* __restrict__ fw3,
    const float* __restrict__ fb3, const float* __restrict__ g,
    const float* __restrict__ be, float* __restrict__ out) {
  __shared__ float ts[512][16];
  __shared__ float c1s[5][512];
  __shared__ float flat[512];
  __shared__ float z1p[2][256];
  __shared__ float z1[256];
  __shared__ float z2p[2][128];
  __shared__ float z2[128];
  __shared__ float z3[96];
  int b = blockIdx.x, tid = threadIdx.x;
  const float4* tsrc = (const float4*)(t + (long)b * 8192);
  float4* tdst = (float4*)&ts[0][0];
#pragma unroll
  for (int i = 0; i < 4; ++i) tdst[tid + i * 512] = tsrc[tid + i * 512];
  __syncthreads();
#pragma unroll
  for (int i = 0; i < 5; ++i) {
    int idx = tid + i * 512;  // 0..2559
    int o = idx >> 9, s = idx & 511;
    float a = b1[o];
#pragma unroll
    for (int k = 0; k < 3; ++k) {
      int ss = s + k - 1;
      if (ss >= 0 && ss < 512) a += ts[ss][o * 3 + k] + bias_t[o * 3 + k];
    }
    c1s[o][s] = eluf(a);
  }
  __syncthreads();
  {
    int r = tid;  // 0..511
    int o = r >> 8, sp = r & 255;
    float mx = -1e30f;
#pragma unroll
    for (int sd = 0; sd < 2; ++sd) {
      int s = sp * 2 + sd;
      float a = b2[o];
#pragma unroll
      for (int ic = 0; ic < 5; ++ic)
#pragma unroll
        for (int k = 0; k < 3; ++k) {
          int ss = s + k - 1;
          if (ss >= 0 && ss < 512) a += c1s[ic][ss] * w2[(o * 5 + ic) * 3 + k];
        }
      mx = fmaxf(mx, eluf(a));
    }
    flat[r] = mx;
  }
  __syncthreads();
  {
    int o = tid & 255, part = tid >> 8;
    float a = 0.f;
    const float* wp = fw1 + (long)part * 256 * 256 + o;
    const float* xp = flat + part * 256;
#pragma unroll 8
    for (int i = 0; i < 256; ++i) a += xp[i] * wp[i * 256];
    z1p[part][o] = a;
  }
  __syncthreads();
  if (tid < 256) z1[tid] = eluf(fb1[tid] + z1p[0][tid] + z1p[1][tid]);
  __syncthreads();
  if (tid < 256) {
    int o = tid & 127, part = tid >> 7;
    float a = 0.f;
    const float* wp = fw2 + (long)part * 128 * 128 + o;
    const float* xp = z1 + part * 128;
#pragma unroll 8
    for (int i = 0; i < 128; ++i) a += xp[i] * wp[i * 128];
    z2p[part][o] = a;
  }
  __syncthreads();
  if (tid < 128) z2[tid] = eluf(fb2[tid] + z2p[0][tid] + z2p[1][tid]);
  __syncthreads();
  if (tid < 96) {
    float a = fb3[tid];
#pragma unroll 8
    for (int i = 0; i < 128; ++i) a += z2[i] * fw3[i * 96 + tid];
    z3[tid] = a;
  }
  __syncthreads();
  if (tid < 96) {
    float mu = 0.f;
    for (int j = 0; j < 96; ++j) mu += z3[j];
    mu *= (1.f / 96.f);
    float sq = 0.f;
    for (int j = 0; j < 96; ++j) {
      float d = z3[j] - mu;
      sq += d * d;
    }
    float var = sq * (1.f / 96.f);
    out[b * 96 + tid] = (z3[tid] - mu) / sqrtf(var + 1e-5f) * g[tid] + be[tid];
  }
}

// ---------------------------------------------------------------------------
extern "C" void kernel_launch(void* const* d_in, const int* in_sizes, int n_in,
                              void* d_out, int out_size, void* d_ws,
                              size_t ws_size, hipStream_t stream) {
  (void)in_sizes; (void)n_in; (void)out_size;
  const float* x    = (const float*)d_in[0];
  const float* embW = (const float*)d_in[1];
  const float* embB = (const float*)d_in[2];
  const float* Wq   = (const float*)d_in[3];
  const float* bq   = (const float*)d_in[4];
  const float* Wk   = (const float*)d_in[5];
  const float* bk   = (const float*)d_in[6];
  const float* Wv   = (const float*)d_in[7];
  const float* bv   = (const float*)d_in[8];
  const float* Wo   = (const float*)d_in[9];
  const float* bo   = (const float*)d_in[10];
  const float* c1w  = (const float*)d_in[11];
  const float* c1b  = (const float*)d_in[12];
  const float* c2w  = (const float*)d_in[13];
  const float* c2b  = (const float*)d_in[14];
  const float* f1w  = (const float*)d_in[15];
  const float* f1b  = (const float*)d_in[16];
  const float* f2w  = (const float*)d_in[17];
  const float* f2b_ = (const float*)d_in[18];
  const float* f3w  = (const float*)d_in[19];
  const float* f3b  = (const float*)d_in[20];
  const float* lng  = (const float*)d_in[21];
  const float* lnb  = (const float*)d_in[22];
  float* out = (float*)d_out;

  char* p = (char*)d_ws;
  const size_t NEED = 215736384;
  if (ws_size < NEED) return;
  const long MS = 8388608;  // per-module stride in u16 elements (16 MB)

  u16*   A_pe    = (u16*)(p + 0);
  u16*   WTqkv   = (u16*)(p + 524288);
  float* pb_bias = (float*)(p + 6815744);
  float* EW      = (float*)(p + 6840320);
  u16*   PB      = (u16*)(p + 6938624);
  u16*   ctx4    = (u16*)(p + 13230080);   // 4 x 16.77 MB (attn output)
  u16*   K4      = (u16*)(p + 80338944);
  u16*   VT4     = (u16*)(p + 147447808);
  u16*   WEFFT   = (u16*)(p + 214556672);
  float* bias_t  = (float*)(p + 214622208);
  float* t_buf   = (float*)(p + 214622272);

  prep_misc<<<1865, 256, 0, stream>>>(embB, bq, bk, bv, Wq, Wk, Wv, embW, Wo,
                                      bo, c1w, A_pe, pb_bias, EW, WEFFT,
                                      bias_t, WTqkv);
  gemm_bt<true><<<dim3(4, 4, 12), 256, 0, stream>>>(
      A_pe, 0, 512, WTqkv, pb_bias, (void*)PB, 262144, 512);

  kv_fused<<<dim3(256, 8, 4), 256, 0, stream>>>(x, EW, PB, K4, VT4, MS);
  attn_kernel<<<2048, 512, 0, stream>>>(x, EW, PB, K4, VT4, ctx4, MS);

  t_gemm<<<1024, 64, 0, stream>>>(ctx4, WEFFT, t_buf);
  tail_fused<<<32, 512, 0, stream>>>(t_buf, bias_t, c1b, c2w, c2b, f1w, f1b,
                                     f2w, f2b_, f3w, f3b, lng, lnb, out);
}

// Round 21
// 200.147 us; speedup vs baseline: 1.0455x; 1.0120x over previous
//
#include <hip/hip_runtime.h>
#include <math.h>

typedef unsigned short u16;
typedef unsigned int u32;
typedef __attribute__((ext_vector_type(8))) short short8;
typedef __attribute__((ext_vector_type(4))) float f32x4;
typedef __attribute__((ext_vector_type(16))) float f32x16;
typedef __attribute__((ext_vector_type(4))) u32 u32x4;
typedef __attribute__((ext_vector_type(2))) u32 u32x2;

__device__ inline u16 f2b(float f) {
  u32 u = __builtin_bit_cast(u32, f);
  u32 r = u + 0x7fffu + ((u >> 16) & 1u);
  return (u16)(r >> 16);
}
__device__ inline float b2f(u16 b) {
  return __builtin_bit_cast(float, (u32)b << 16);
}
// HW packed f32->bf16 (RTNE), 1 instruction for 2 values
__device__ inline u32 cvtpk(float lo, float hi) {
  u32 r;
  asm("v_cvt_pk_bf16_f32 %0, %1, %2" : "=v"(r) : "v"(lo), "v"(hi));
  return r;
}
// raw v_exp_f32: D = 2^S0
__device__ inline float exp2hw(float x) {
  float r;
  asm("v_exp_f32 %0, %1" : "=v"(r) : "v"(x));
  return r;
}
__device__ inline float eluf(float x) { return x > 0.f ? x : expf(x) - 1.f; }

__device__ inline f32x4 mfma16(short8 a, short8 b, f32x4 c) {
  return __builtin_amdgcn_mfma_f32_16x16x32_bf16(a, b, c, 0, 0, 0);
}
__device__ inline f32x16 mfma32(short8 a, short8 b, f32x16 c) {
  return __builtin_amdgcn_mfma_f32_32x32x16_bf16(a, b, c, 0, 0, 0);
}
__device__ inline void gload16(const u16* g, u16* l) {
  __builtin_amdgcn_global_load_lds((__attribute__((address_space(1))) void*)(g),
                                   (__attribute__((address_space(3))) void*)(l),
                                   16, 0, 0);
}

// ---------------------------------------------------------------------------
// prep_misc: prep_pe + pb_bias + EW + WEFF/bias_t + transw (all one launch)
// ---------------------------------------------------------------------------
__global__ __launch_bounds__(256) void prep_misc(
    const float* __restrict__ emb_b, const float* __restrict__ bq,
    const float* __restrict__ bk, const float* __restrict__ bv,
    const float* __restrict__ Wq, const float* __restrict__ Wk,
    const float* __restrict__ Wv, const float* __restrict__ embW,
    const float* __restrict__ Wo, const float* __restrict__ bo,
    const float* __restrict__ w1, u16* __restrict__ A_pe,
    float* __restrict__ pb_bias, float* __restrict__ EW,
    u16* __restrict__ WEFFT, float* __restrict__ bias_t,
    u16* __restrict__ WTqkv) {
  __shared__ float smem[64 * 65];
  const int bid = blockIdx.x, t = threadIdx.x;
  if (bid < 512) {
    int s = bid;
    float div = __expf((2.f * t) * (-9.210340371976184f / 512.f));
    float arg = (float)s * div;
    A_pe[s * 512 + 2 * t] = f2b(__sinf(arg) + emb_b[2 * t]);
    A_pe[s * 512 + 2 * t + 1] = f2b(__cosf(arg) + emb_b[2 * t + 1]);
  } else if (bid < 536) {
    int i = (bid - 512) * 256 + t;  // 0..6143
    int z = i >> 9, e = i & 511;
    int ty = z >> 2, m = z & 3;
    const float* bp = (ty == 0) ? bq : (ty == 1) ? bk : bv;
    pb_bias[i] = bp[m * 512 + e];
  } else if (bid < 584) {
    int idx = bid - 536;
    int z = idx >> 2, ch = idx & 3;
    const float* W =
        ((z < 4) ? Wq : (z < 8) ? Wk : Wv) + (long)(z & 3) * 262144;
    int el = t & 127, dh = t >> 7;
    int e = ch * 128 + el;
    float a[4] = {};
    for (int d = dh * 256; d < dh * 256 + 256; ++d) {
      float wv = W[(long)d * 512 + e];
#pragma unroll
      for (int f = 0; f < 4; ++f) a[f] += embW[f * 512 + d] * wv;
    }
#pragma unroll
    for (int f = 0; f < 4; ++f) smem[(dh * 4 + f) * 128 + el] = a[f];
    __syncthreads();
    if (t < 128) {
#pragma unroll
      for (int f = 0; f < 4; ++f)
        EW[((long)z * 4 + f) * 512 + e] =
            smem[f * 128 + el] + smem[(4 + f) * 128 + el];
    }
  } else if (bid < 1097) {
    const int wb = bid - 584;  // 0..512
    const int w = t >> 6, l = t & 63;
    if (wb < 512) {
      int idx = wb * 4 + w;  // 0..2047
      int m = idx >> 9, d = idx & 511;
      const float* wrow = Wo + ((long)m * 512 + d) * 512;
      float a[15] = {};
#pragma unroll
      for (int i = 0; i < 8; ++i) {
        int e = l * 8 + i;
        float wv = wrow[e];
#pragma unroll
        for (int o = 0; o < 5; ++o)
#pragma unroll
          for (int k = 0; k < 3; ++k)
            a[o * 3 + k] += wv * w1[((long)o * 2048 + m * 512 + e) * 3 + k];
      }
#pragma unroll
      for (int j = 0; j < 15; ++j) {
        float v = a[j];
        for (int o = 1; o < 64; o <<= 1) v += __shfl_xor(v, o);
        if (l == 0) WEFFT[((long)m * 16 + j) * 512 + d] = f2b(v);
      }
      if (l == 0) WEFFT[((long)m * 16 + 15) * 512 + d] = 0;
    } else if (w == 0) {
      float a[15] = {};
      for (int c = l; c < 2048; c += 64) {
        float bv = bo[c];
#pragma unroll
        for (int o = 0; o < 5; ++o)
#pragma unroll
          for (int k = 0; k < 3; ++k)
            a[o * 3 + k] += bv * w1[((long)o * 2048 + c) * 3 + k];
      }
#pragma unroll
      for (int j = 0; j < 15; ++j) {
        float v = a[j];
        for (int o = 1; o < 64; o <<= 1) v += __shfl_xor(v, o);
        if (l == 0) bias_t[j] = v;
      }
      if (l == 0) bias_t[15] = 0.f;
    }
  } else {
    // transw: bf16-transpose one 64x64 tile of one QKV weight matrix
    int bidt = bid - 1097;  // 0..767
    int mid = bidt >> 6, rest = bidt & 63;
    int d0 = (rest >> 3) * 64, e0 = (rest & 7) * 64;
    const float* W =
        ((mid < 4) ? Wq : (mid < 8) ? Wk : Wv) + (long)(mid & 3) * 262144;
    u16* WT = WTqkv + (long)mid * 262144;
    float(*tile)[65] = (float(*)[65])smem;
    int dr = t >> 2, ec = (t & 3) * 16;
#pragma unroll
    for (int j = 0; j < 16; j += 4) {
      float4 v = *(const float4*)&W[(long)(d0 + dr) * 512 + e0 + ec + j];
      tile[dr][ec + j] = v.x;
      tile[dr][ec + j + 1] = v.y;
      tile[dr][ec + j + 2] = v.z;
      tile[dr][ec + j + 3] = v.w;
    }
    __syncthreads();
    int er = t >> 2, dc = (t & 3) * 16;
    u16 tmp[16] __attribute__((aligned(16)));
#pragma unroll
    for (int j = 0; j < 16; ++j) tmp[j] = f2b(tile[dc + j][er]);
    *(short8*)&WT[(long)(e0 + er) * 512 + d0 + dc] = *(short8*)&tmp[0];
    *(short8*)&WT[(long)(e0 + er) * 512 + d0 + dc + 8] = *(short8*)&tmp[8];
  }
}

// ---------------------------------------------------------------------------
// bf16 GEMM; 3-deep LDS pipeline, one barrier per K-step, fully unrolled.
// ---------------------------------------------------------------------------
template <bool OBF>
__global__ __launch_bounds__(256) void gemm_bt(
    const u16* __restrict__ A, long sAz, int lda, const u16* __restrict__ BT,
    const float* __restrict__ bias, void* __restrict__ out, long sOz, int ldo) {
  __shared__ u16 As[3][128 * 32];
  __shared__ u16 Bs[3][128 * 32];
  const int z = blockIdx.z;
  const int tid = threadIdx.x, w = tid >> 6, l = tid & 63;
  const long row0 = (long)blockIdx.y * 128;
  const u16* Ab = A + (long)z * sAz + row0 * lda;
  const u16* Bb = BT + (long)z * 262144 + (long)blockIdx.x * 128 * 512;
  const u16* ga = Ab + (long)(w * 32 + (l >> 2)) * lda + (l & 3) * 8;
  const u16* gb = Bb + (long)(w * 32 + (l >> 2)) * 512 + (l & 3) * 8;
  f32x4 acc[4][4] = {};
  const int wr = (w >> 1) * 64, wc = (w & 1) * 64;

#define GSTAGE(BF, KT)                                                        \
  {                                                                           \
    gload16(ga + (KT)*32, &As[BF][w * 32 * 32]);                              \
    gload16(ga + (KT)*32 + 16 * lda, &As[BF][w * 32 * 32 + 16 * 32]);         \
    gload16(gb + (KT)*32, &Bs[BF][w * 32 * 32]);                              \
    gload16(gb + (KT)*32 + 16 * 512, &Bs[BF][w * 32 * 32 + 16 * 32]);         \
  }

#define GTILE(KT, CUR, NXT)                                                   \
  {                                                                           \
    if ((KT) < 15) {                                                          \
      GSTAGE(NXT, (KT) + 1);                                                  \
      asm volatile("s_waitcnt vmcnt(4)" ::: "memory");                        \
    } else {                                                                  \
      asm volatile("s_waitcnt vmcnt(0)" ::: "memory");                        \
    }                                                                         \
    __builtin_amdgcn_s_barrier();                                             \
    __builtin_amdgcn_sched_barrier(0);                                        \
    short8 af[4], bf[4];                                                      \
    _Pragma("unroll") for (int i = 0; i < 4; ++i) af[i] =                     \
        *(const short8*)&As[CUR][(wr + i * 16 + (l & 15)) * 32 +              \
                                 (l >> 4) * 8];                               \
    _Pragma("unroll") for (int i = 0; i < 4; ++i) bf[i] =                     \
        *(const short8*)&Bs[CUR][(wc + i * 16 + (l & 15)) * 32 +              \
                                 (l >> 4) * 8];                               \
    _Pragma("unroll") for (int i = 0; i < 4; ++i) _Pragma("unroll")           \
        for (int j = 0; j < 4; ++j) acc[i][j] =                               \
            mfma16(af[i], bf[j], acc[i][j]);                                  \
    __builtin_amdgcn_sched_barrier(0);                                        \
  }

  GSTAGE(0, 0);
  GTILE(0, 0, 1);  GTILE(1, 1, 2);  GTILE(2, 2, 0);  GTILE(3, 0, 1);
  GTILE(4, 1, 2);  GTILE(5, 2, 0);  GTILE(6, 0, 1);  GTILE(7, 1, 2);
  GTILE(8, 2, 0);  GTILE(9, 0, 1);  GTILE(10, 1, 2); GTILE(11, 2, 0);
  GTILE(12, 0, 1); GTILE(13, 1, 2); GTILE(14, 2, 0); GTILE(15, 0, 1);
#undef GTILE
#undef GSTAGE

  const int colB = blockIdx.x * 128 + wc;
#pragma unroll
  for (int i = 0; i < 4; ++i)
#pragma unroll
    for (int j = 0; j < 4; ++j) {
      int col = colB + j * 16 + (l & 15);
      float bb = bias[(long)z * 512 + col];
#pragma unroll
      for (int q = 0; q < 4; ++q) {
        long r = row0 + wr + i * 16 + (l >> 4) * 4 + q;
        float v = acc[i][j][q] + bb;
        if (OBF)
          ((u16*)out)[(long)z * sOz + r * ldo + col] = f2b(v);
        else
          ((float*)out)[(long)z * sOz + r * ldo + col] = v;
      }
    }
}

// ---------------------------------------------------------------------------
// fused KV + V-transpose (Q generated inside attention).
// ---------------------------------------------------------------------------
__global__ __launch_bounds__(256) void kv_fused(
    const float* __restrict__ x, const float* __restrict__ EW,
    const u16* __restrict__ PB, u16* __restrict__ K, u16* __restrict__ VT,
    long mstride) {
  __shared__ float ews[2][4][64];
  __shared__ u16 vtile[64][72];
  const int bh = blockIdx.x;  // b*8+h
  const int st = blockIdx.y;
  const int m = blockIdx.z;
  const int b = bh >> 3, h = bh & 7;
  const int hoff = h * 64;
  const int t = threadIdx.x;
  if (t < 128) {
    int ir = t >> 6, dk = t & 63;  // ir: 0=K(z=4+m), 1=V(z=8+m)
    int z = (ir + 1) * 4 + m;
#pragma unroll
    for (int f = 0; f < 4; ++f)
      ews[ir][f][dk] = EW[((long)z * 4 + f) * 512 + hoff + dk];
  }
  __syncthreads();
  const int sr = t >> 2, cq = t & 3;
  const int s = st * 64 + sr;
  const long rid = (long)b * 512 + s;
  const float* xr = x + rid * 7;
  const float xd = xr[3 + m], x0 = xr[0], x1 = xr[1], x2 = xr[2];
  const long obase = (long)m * mstride + rid * 512 + hoff + cq * 16;

  float res[2][16];
#pragma unroll
  for (int ir = 0; ir < 2; ++ir) {
    int z = (ir + 1) * 4 + m;
    const u16* pbp = PB + (((long)z * 512 + s)) * 512 + hoff + cq * 16;
    short8 pbv0 = *(const short8*)pbp;
    short8 pbv1 = *(const short8*)(pbp + 8);
#pragma unroll
    for (int j = 0; j < 16; ++j) {
      int dk = cq * 16 + j;
      u16 pb = (u16)(j < 8 ? pbv0[j] : pbv1[j - 8]);
      res[ir][j] = xd * ews[ir][0][dk] + x0 * ews[ir][1][dk] +
                   x1 * ews[ir][2][dk] + x2 * ews[ir][3][dk] + b2f(pb);
    }
  }
  {
    float ss = 0.f;
#pragma unroll
    for (int j = 0; j < 16; ++j) ss += res[0][j] * res[0][j];
    ss += __shfl_xor(ss, 1);
    ss += __shfl_xor(ss, 2);
    float sc = 1.f / fmaxf(sqrtf(ss), 1e-12f);
    u32 o[8];
#pragma unroll
    for (int jj = 0; jj < 8; ++jj)
      o[jj] = cvtpk(res[0][2 * jj] * sc, res[0][2 * jj + 1] * sc);
    *(u32x4*)&K[obase] = *(u32x4*)&o[0];
    *(u32x4*)&K[obase + 8] = *(u32x4*)&o[4];
  }
  {
    u32 o[8];
#pragma unroll
    for (int jj = 0; jj < 8; ++jj)
      o[jj] = cvtpk(res[1][2 * jj], res[1][2 * jj + 1]);
    *(short8*)&vtile[sr][cq * 16] = *(short8*)&o[0];
    *(short8*)&vtile[sr][cq * 16 + 8] = *(short8*)&o[4];
  }
  __syncthreads();
  {
    int kr = t >> 2, sc2 = (t & 3) * 16;
    u16 tmp[16] __attribute__((aligned(16)));
#pragma unroll
    for (int j = 0; j < 16; ++j) tmp[j] = vtile[sc2 + j][kr];
    long gdst = (long)m * mstride + ((long)bh * 64 + kr) * 512 + st * 64 + sc2;
    *(short8*)&VT[gdst] = *(short8*)&tmp[0];
    *(short8*)&VT[gdst + 8] = *(short8*)&tmp[8];
  }
}

// ---------------------------------------------------------------------------
// flash attention, max-free, 32x32 swapped-operand; 8-wave blocks; XCD
// swizzle; 3-deep LDS pipeline, ONE barrier per tile, fully unrolled.
// Q generated in-block (pack-early); log2(e) folded into Q's normalization
// scale (no extra rounding vs round-20: replaces the same scale constant),
// so P = v_exp(S) = 2^S directly. 16B ctx stores via permlane pairing.
// ---------------------------------------------------------------------------
__global__ __launch_bounds__(512, 4) void attn_kernel(
    const float* __restrict__ x, const float* __restrict__ EW,
    const u16* __restrict__ PB, const u16* __restrict__ Kg,
    const u16* __restrict__ VTg, u16* __restrict__ ctxg, long mstride) {
  __shared__ u16 Kb[3][64][64];
  __shared__ u16 Vb[3][64][64];
  __shared__ float ewsq[64][4];
  const int wgid = (blockIdx.x & 7) * 256 + (blockIdx.x >> 3);
  const int qp = wgid & 1;        // 0..1, 256 q-rows each
  const int mz = wgid >> 1;
  const int m = mz & 3;           // module
  const int bh = mz >> 2;         // b*8+h
  const u16* K = Kg + (long)m * mstride;
  const u16* VT = VTg + (long)m * mstride;
  u16* ctx = ctxg + (long)m * mstride;
  const int b = bh >> 3, h = bh & 7;
  const int tid = threadIdx.x, w = tid >> 6, l = tid & 63;
  const int lq = l & 31, hi = l >> 5, l7 = l & 7;
  const long rowbase = (long)b * 512;
  const int hoff = h * 64;
  const int rw = l >> 3, gch = (l & 7) ^ rw;
  const int qrow = qp * 256 + w * 32;

  const u16* Kgbase = K + rowbase * 512 + hoff + gch * 8;
  const u16* Vgbase = VT + (long)bh * 64 * 512 + gch * 8;

#define STAGE(bf, kt)                                                         \
  {                                                                           \
    int rr = w * 8;                                                           \
    gload16(Kgbase + (long)((kt)*64 + rr + rw) * 512, &Kb[bf][rr][0]);        \
    gload16(Vgbase + (long)(rr + rw) * 512 + (kt)*64, &Vb[bf][rr][0]);        \
  }

  // stage Q's EW slice transposed [64][4]
  if (tid < 256) {
    int dk = tid >> 2, f = tid & 3;
    ewsq[dk][f] = EW[((long)m * 4 + f) * 512 + hoff + dk];
  }
  STAGE(0, 0);  // tile-0 loads fly under Q-gen
  __syncthreads();

  // Q-gen, pack-early: row s_q = qrow+lq, dk = dc*16+hi*8+j
  short8 qf[4];
  {
    const int s_q = qrow + lq;
    const float* xr = x + (rowbase + s_q) * 7;
    const float xd = xr[3 + m], x0 = xr[0], x1 = xr[1], x2 = xr[2];
    const u16* pbq = PB + ((long)m * 512 + s_q) * 512 + hoff + hi * 8;
    u32 qpk[16];
    float ss = 0.f;
#pragma unroll
    for (int dc = 0; dc < 4; ++dc) {
      short8 pbv = *(const short8*)(pbq + dc * 16);
      float v[8];
#pragma unroll
      for (int j = 0; j < 8; ++j) {
        int dk = dc * 16 + hi * 8 + j;
        float4 e = *(const float4*)&ewsq[dk][0];
        v[j] = xd * e.x + x0 * e.y + x1 * e.z + x2 * e.w + b2f((u16)pbv[j]);
        ss += v[j] * v[j];
      }
#pragma unroll
      for (int jj = 0; jj < 4; ++jj)
        qpk[dc * 4 + jj] = cvtpk(v[2 * jj], v[2 * jj + 1]);
    }
    ss += __shfl_xor(ss, 32);  // partner holds the complementary 32 dk
    // fold log2(e) into the normalization scale: S = (log2e*Q).K, P = 2^S
    float sc = 1.4426950408889634f / fmaxf(sqrtf(ss), 1e-12f);
#pragma unroll
    for (int dc = 0; dc < 4; ++dc) {
      u32x4 pk;
#pragma unroll
      for (int jj = 0; jj < 4; ++jj) {
        u32 pv = qpk[dc * 4 + jj];
        pk[jj] = cvtpk(b2f((u16)pv) * sc, b2f((u16)(pv >> 16)) * sc);
      }
      qf[dc] = __builtin_bit_cast(short8, pk);
    }
  }

  short8 ones;
#pragma unroll
  for (int i = 0; i < 8; ++i) ones[i] = (short)0x3F80;  // bf16 1.0

  f32x16 o_acc[2] = {};
  f32x16 l_acc = {};

#define TILE(KT, CUR, NXT)                                                    \
  {                                                                           \
    if ((KT) < 7) {                                                           \
      STAGE(NXT, (KT) + 1);                                                   \
      asm volatile("s_waitcnt vmcnt(2)" ::: "memory");                        \
    } else {                                                                  \
      asm volatile("s_waitcnt vmcnt(0)" ::: "memory");                        \
    }                                                                         \
    __builtin_amdgcn_s_barrier();                                             \
    __builtin_amdgcn_sched_barrier(0);                                        \
    __builtin_amdgcn_s_setprio(1);                                            \
    _Pragma("unroll") for (int ktile = 0; ktile < 2; ++ktile) {               \
      f32x16 s = {};                                                          \
      _Pragma("unroll") for (int dc = 0; dc < 4; ++dc) {                      \
        short8 kf = *(const short8*)((const char*)&Kb[CUR][ktile * 32 + lq]   \
                                         [0] +                                \
                                     (((dc * 2 + hi) ^ l7) * 16));            \
        s = mfma32(kf, qf[dc], s);                                            \
      }                                                                       \
      float p[16];                                                            \
      _Pragma("unroll") for (int r = 0; r < 16; ++r) p[r] = exp2hw(s[r]);     \
      u32 s0a = cvtpk(p[0], p[1]), s0b = cvtpk(p[4], p[5]);                   \
      u32 s1a = cvtpk(p[2], p[3]), s1b = cvtpk(p[6], p[7]);                   \
      u32 s2a = cvtpk(p[8], p[9]), s2b = cvtpk(p[12], p[13]);                 \
      u32 s3a = cvtpk(p[10], p[11]), s3b = cvtpk(p[14], p[15]);               \
      asm("v_permlane32_swap_b32 %0, %1" : "+v"(s0a), "+v"(s0b));             \
      asm("v_permlane32_swap_b32 %0, %1" : "+v"(s1a), "+v"(s1b));             \
      asm("v_permlane32_swap_b32 %0, %1" : "+v"(s2a), "+v"(s2b));             \
      asm("v_permlane32_swap_b32 %0, %1" : "+v"(s3a), "+v"(s3b));             \
      u32x4 f0v = {s0a, s1a, s0b, s1b};                                       \
      u32x4 f1v = {s2a, s3a, s2b, s3b};                                       \
      short8 bf0 = __builtin_bit_cast(short8, f0v);                           \
      short8 bf1 = __builtin_bit_cast(short8, f1v);                           \
      _Pragma("unroll") for (int kk2 = 0; kk2 < 2; ++kk2) {                   \
        const int kc = ktile * 2 + kk2;                                       \
        short8 pb = kk2 ? bf1 : bf0;                                          \
        l_acc = mfma32(ones, pb, l_acc);                                      \
        _Pragma("unroll") for (int dt = 0; dt < 2; ++dt) {                    \
          short8 vf =                                                         \
              *(const short8*)((const char*)&Vb[CUR][dt * 32 + lq][0] +       \
                               (((kc * 2 + hi) ^ l7) * 16));                  \
          o_acc[dt] = mfma32(vf, pb, o_acc[dt]);                              \
        }                                                                     \
      }                                                                       \
    }                                                                         \
    __builtin_amdgcn_s_setprio(0);                                            \
    __builtin_amdgcn_sched_barrier(0);                                        \
  }

  TILE(0, 0, 1);
  TILE(1, 1, 2);
  TILE(2, 2, 0);
  TILE(3, 0, 1);
  TILE(4, 1, 2);
  TILE(5, 2, 0);
  TILE(6, 0, 1);
  TILE(7, 1, 2);
#undef TILE
#undef STAGE
  // epilogue: 16B coalesced ctx stores via permlane pairing.
  const float inv = 1.f / l_acc[0];
  u16* crow = ctx + (rowbase + qrow + lq) * 512 + hoff;
#pragma unroll
  for (int dt = 0; dt < 2; ++dt) {
    u32 g00 = cvtpk(o_acc[dt][0] * inv, o_acc[dt][1] * inv);
    u32 g01 = cvtpk(o_acc[dt][2] * inv, o_acc[dt][3] * inv);
    u32 g10 = cvtpk(o_acc[dt][4] * inv, o_acc[dt][5] * inv);
    u32 g11 = cvtpk(o_acc[dt][6] * inv, o_acc[dt][7] * inv);
    u32 g20 = cvtpk(o_acc[dt][8] * inv, o_acc[dt][9] * inv);
    u32 g21 = cvtpk(o_acc[dt][10] * inv, o_acc[dt][11] * inv);
    u32 g30 = cvtpk(o_acc[dt][12] * inv, o_acc[dt][13] * inv);
    u32 g31 = cvtpk(o_acc[dt][14] * inv, o_acc[dt][15] * inv);
    asm("v_permlane32_swap_b32 %0, %1" : "+v"(g00), "+v"(g20));
    asm("v_permlane32_swap_b32 %0, %1" : "+v"(g01), "+v"(g21));
    asm("v_permlane32_swap_b32 %0, %1" : "+v"(g10), "+v"(g30));
    asm("v_permlane32_swap_b32 %0, %1" : "+v"(g11), "+v"(g31));
    u32x4 st0 = {g00, g01, g20, g21};
    u32x4 st1 = {g10, g11, g30, g31};
    const int base = dt * 32 + hi * 16;
    *(u32x4*)&crow[base] = st0;
    *(u32x4*)&crow[base + 8] = st1;
  }
}

// ---------------------------------------------------------------------------
// t[r][j] = sum_m ctx_m[r][:] . WEFFT[m][j][:]
// ---------------------------------------------------------------------------
__global__ __launch_bounds__(64) void t_gemm(const u16* __restrict__ ctx4,
                                             const u16* __restrict__ WEFFT,
                                             float* __restrict__ t) {
  const int l = threadIdx.x;
  const long r0 = (long)blockIdx.x * 16;
  f32x4 acc = {};
#pragma unroll
  for (int m = 0; m < 4; ++m) {
    const u16* A =
        ctx4 + (long)m * 8388608 + (r0 + (l & 15)) * 512 + (l >> 4) * 8;
    const u16* Bb = WEFFT + m * 8192 + (l & 15) * 512 + (l >> 4) * 8;
#pragma unroll
    for (int kt = 0; kt < 16; ++kt) {
      short8 af = *(const short8*)(A + kt * 32);
      short8 bf = *(const short8*)(Bb + kt * 32);
      acc = mfma16(af, bf, acc);
    }
  }
#pragma unroll
  for (int q = 0; q < 4; ++q)
    t[(r0 + (l >> 4) * 4 + q) * 16 + (l & 15)] = acc[q];
}

// ---------------------------------------------------------------------------
// tail_fused: c1 + conv2 + pool + fc1/fc2/fc3 + LN — one block per batch
// ---------------------------------------------------------------------------
__global__ __launch_bounds__(512) void tail_fused(
    const float* __restrict__ t, const float* __restrict__ bias_t,
    const float* __restrict__ b1, const float* __restrict__ w2,
    const float* __restrict__ b2, const float* __restrict__ fw1,
    const float* __restrict__ fb1, const float* __restrict__ fw2,
    const float* __restrict__ fb2, const float* __restrict__ fw3,
    const float* __restrict__ fb3, const float* __restrict__ g,
    const float* __restrict__ be, float* __restrict__ out) {
  __shared__ float ts[512][16];
  __shared__ float c1s[5][512];
  __shared__ float flat[512];
  __shared__ float z1p[2][256];
  __shared__ float z1[256];
  __shared__ float z2p[2][128];
  __shared__ float z2[128];
  __shared__ float z3[96];
  int b = blockIdx.x, tid = threadIdx.x;
  const float4* tsrc = (const float4*)(t + (long)b * 8192);
  float4* tdst = (float4*)&ts[0][0];
#pragma unroll
  for (int i = 0; i < 4; ++i) tdst[tid + i * 512] = tsrc[tid + i * 512];
  __syncthreads();
#pragma unroll
  for (int i = 0; i < 5; ++i) {
    int idx = tid + i * 512;  // 0..2559
    int o = idx >> 9, s = idx & 511;
    float a = b1[o];
#pragma unroll
    for (int k = 0; k < 3; ++k) {
      int ss = s + k - 1;
      if (ss >= 0 && ss < 512) a += ts[ss][o * 3 + k] + bias_t[o * 3 + k];
    }
    c1s[o][s] = eluf(a);
  }
  __syncthreads();
  {
    int r = tid;  // 0..511
    int o = r >> 8, sp = r & 255;
    float mx = -1e30f;
#pragma unroll
    for (int sd = 0; sd < 2; ++sd) {
      int s = sp * 2 + sd;
      float a = b2[o];
#pragma unroll
      for (int ic = 0; ic < 5; ++ic)
#pragma unroll
        for (int k = 0; k < 3; ++k) {
          int ss = s + k - 1;
          if (ss >= 0 && ss < 512) a += c1s[ic][ss] * w2[(o * 5 + ic) * 3 + k];
        }
      mx = fmaxf(mx, eluf(a));
    }
    flat[r] = mx;
  }
  __syncthreads();
  {
    int o = tid & 255, part = tid >> 8;
    float a = 0.f;
    const float* wp = fw1 + (long)part * 256 * 256 + o;
    const float* xp = flat + part * 256;
#pragma unroll 8
    for (int i = 0; i < 256; ++i) a += xp[i] * wp[i * 256];
    z1p[part][o] = a;
  }
  __syncthreads();
  if (tid < 256) z1[tid] = eluf(fb1[tid] + z1p[0][tid] + z1p[1][tid]);
  __syncthreads();
  if (tid < 256) {
    int o = tid & 127, part = tid >> 7;
    float a = 0.f;
    const float* wp = fw2 + (long)part * 128 * 128 + o;
    const float* xp = z1 + part * 128;
#pragma unroll 8
    for (int i = 0; i < 128; ++i) a += xp[i] * wp[i * 128];
    z2p[part][o] = a;
  }
  __syncthreads();
  if (tid < 128) z2[tid] = eluf(fb2[tid] + z2p[0][tid] + z2p[1][tid]);
  __syncthreads();
  if (tid < 96) {
    float a = fb3[tid];
#pragma unroll 8
    for (int i = 0; i < 128; ++i) a += z2[i] * fw3[i * 96 + tid];
    z3[tid] = a;
  }
  __syncthreads();
  if (tid < 96) {
    float mu = 0.f;
    for (int j = 0; j < 96; ++j) mu += z3[j];
    mu *= (1.f / 96.f);
    float sq = 0.f;
    for (int j = 0; j < 96; ++j) {
      float d = z3[j] - mu;
      sq += d * d;
    }
    float var = sq * (1.f / 96.f);
    out[b * 96 + tid] = (z3[tid] - mu) / sqrtf(var + 1e-5f) * g[tid] + be[tid];
  }
}

// ---------------------------------------------------------------------------
extern "C" void kernel_launch(void* const* d_in, const int* in_sizes, int n_in,
                              void* d_out, int out_size, void* d_ws,
                              size_t ws_size, hipStream_t stream) {
  (void)in_sizes; (void)n_in; (void)out_size;
  const float* x    = (const float*)d_in[0];
  const float* embW = (const float*)d_in[1];
  const float* embB = (const float*)d_in[2];
  const float* Wq   = (const float*)d_in[3];
  const float* bq   = (const float*)d_in[4];
  const float* Wk   = (const float*)d_in[5];
  const float* bk   = (const float*)d_in[6];
  const float* Wv   = (const float*)d_in[7];
  const float* bv   = (const float*)d_in[8];
  const float* Wo   = (const float*)d_in[9];
  const float* bo   = (const float*)d_in[10];
  const float* c1w  = (const float*)d_in[11];
  const float* c1b  = (const float*)d_in[12];
  const float* c2w  = (const float*)d_in[13];
  const float* c2b  = (const float*)d_in[14];
  const float* f1w  = (const float*)d_in[15];
  const float* f1b  = (const float*)d_in[16];
  const float* f2w  = (const float*)d_in[17];
  const float* f2b_ = (const float*)d_in[18];
  const float* f3w  = (const float*)d_in[19];
  const float* f3b  = (const float*)d_in[20];
  const float* lng  = (const float*)d_in[21];
  const float* lnb  = (const float*)d_in[22];
  float* out = (float*)d_out;

  char* p = (char*)d_ws;
  const size_t NEED = 215736384;
  if (ws_size < NEED) return;
  const long MS = 8388608;  // per-module stride in u16 elements (16 MB)

  u16*   A_pe    = (u16*)(p + 0);
  u16*   WTqkv   = (u16*)(p + 524288);
  float* pb_bias = (float*)(p + 6815744);
  float* EW      = (float*)(p + 6840320);
  u16*   PB      = (u16*)(p + 6938624);
  u16*   ctx4    = (u16*)(p + 13230080);   // 4 x 16.77 MB (attn output)
  u16*   K4      = (u16*)(p + 80338944);
  u16*   VT4     = (u16*)(p + 147447808);
  u16*   WEFFT   = (u16*)(p + 214556672);
  float* bias_t  = (float*)(p + 214622208);
  float* t_buf   = (float*)(p + 214622272);

  prep_misc<<<1865, 256, 0, stream>>>(embB, bq, bk, bv, Wq, Wk, Wv, embW, Wo,
                                      bo, c1w, A_pe, pb_bias, EW, WEFFT,
                                      bias_t, WTqkv);
  gemm_bt<true><<<dim3(4, 4, 12), 256, 0, stream>>>(
      A_pe, 0, 512, WTqkv, pb_bias, (void*)PB, 262144, 512);

  kv_fused<<<dim3(256, 8, 4), 256, 0, stream>>>(x, EW, PB, K4, VT4, MS);
  attn_kernel<<<2048, 512, 0, stream>>>(x, EW, PB, K4, VT4, ctx4, MS);

  t_gemm<<<1024, 64, 0, stream>>>(ctx4, WEFFT, t_buf);
  tail_fused<<<32, 512, 0, stream>>>(t_buf, bias_t, c1b, c2w, c2b, f1w, f1b,
                                     f2w, f2b_, f3w, f3b, lng, lnb, out);
}